// Round 8
// baseline (1142.038 us; speedup 1.0000x reference)
//
#include <hip/hip_runtime.h>
#include <stdint.h>

typedef __bf16 bf16_t;
typedef __bf16 bf16x8 __attribute__((ext_vector_type(8)));
typedef __bf16 bf16x4 __attribute__((ext_vector_type(4)));
typedef float f32x4 __attribute__((ext_vector_type(4)));
typedef unsigned short ushort_t;

#define CC 768
#define HD 3072
#define TB 196
#define HWD 14
#define EPSF 1e-5f
#define INV_T (1.0f/196.0f)

// ---------------- helpers ----------------
__device__ __forceinline__ float wave_sum(float v) {
#pragma unroll
  for (int off = 32; off > 0; off >>= 1) v += __shfl_xor(v, off, 64);
  return v;
}

__device__ __forceinline__ void async_copy16(const void* g, void* l) {
  typedef __attribute__((address_space(3))) uint32_t lds_u32;
  typedef __attribute__((address_space(1))) const uint32_t glb_u32;
  glb_u32* gp = (glb_u32*)(uintptr_t)g;
  lds_u32* lp = (lds_u32*)(uint32_t)(uintptr_t)l;
  __builtin_amdgcn_global_load_lds(gp, lp, 16, 0, 0);
}

#define SCHED_FENCE() asm volatile("" ::: "memory")
#define BAR() asm volatile("s_barrier" ::: "memory")
#define LGKM0() asm volatile("s_waitcnt lgkmcnt(0)" ::: "memory")

// ---------------- LN0 (normalized row to XB + stats of output row) ----------------
__global__ __launch_bounds__(256) void k_ln0(const float* __restrict__ in,
                                             const float* __restrict__ g,
                                             const float* __restrict__ b,
                                             float* __restrict__ out,
                                             float* __restrict__ st, int M) {
  int row = blockIdx.x * 4 + (threadIdx.x >> 6);
  if (row >= M) return;
  int lane = threadIdx.x & 63;
  const float* rp = in + (size_t)row * CC;
  int c0 = lane * 4;
  f32x4 x[3];
#pragma unroll
  for (int s = 0; s < 3; ++s) x[s] = *(const f32x4*)(rp + s * 256 + c0);
  float sum = 0.f;
#pragma unroll
  for (int s = 0; s < 3; ++s)
#pragma unroll
    for (int j = 0; j < 4; ++j) sum += x[s][j];
  float mean = wave_sum(sum) * (1.0f / CC);
  float s2 = 0.f;
#pragma unroll
  for (int s = 0; s < 3; ++s)
#pragma unroll
    for (int j = 0; j < 4; ++j) { float d = x[s][j] - mean; s2 += d * d; }
  float rs = rsqrtf(wave_sum(s2) * (1.0f / CC) + EPSF);
  float* op = out + (size_t)row * CC;
  f32x4 o[3];
  float sum2 = 0.f;
#pragma unroll
  for (int s = 0; s < 3; ++s) {
    int cc = s * 256 + c0;
    f32x4 gg = *(const f32x4*)(g + cc);
    f32x4 bb = *(const f32x4*)(b + cc);
#pragma unroll
    for (int j = 0; j < 4; ++j) {
      o[s][j] = (x[s][j] - mean) * rs * gg[j] + bb[j];
      sum2 += o[s][j];
    }
    *(f32x4*)(op + cc) = o[s];
  }
  float mean2 = wave_sum(sum2) * (1.0f / CC);
  float q2 = 0.f;
#pragma unroll
  for (int s = 0; s < 3; ++s)
#pragma unroll
    for (int j = 0; j < 4; ++j) { float d = o[s][j] - mean2; q2 += d * d; }
  float rs2 = rsqrtf(wave_sum(q2) * (1.0f / CC) + EPSF);
  if (lane == 0) { st[2 * row] = mean2; st[2 * row + 1] = rs2; }
}

// ---------------- per-row mean/rstd ----------------
__global__ __launch_bounds__(256) void k_stats(const float* __restrict__ in,
                                               float* __restrict__ st, int M) {
  int row = blockIdx.x * 4 + (threadIdx.x >> 6);
  if (row >= M) return;
  int lane = threadIdx.x & 63;
  const float* rp = in + (size_t)row * CC;
  int c0 = lane * 4;
  f32x4 x[3];
#pragma unroll
  for (int s = 0; s < 3; ++s) x[s] = *(const f32x4*)(rp + s * 256 + c0);
  float sum = 0.f;
#pragma unroll
  for (int s = 0; s < 3; ++s)
#pragma unroll
    for (int j = 0; j < 4; ++j) sum += x[s][j];
  float mean = wave_sum(sum) * (1.0f / CC);
  float s2 = 0.f;
#pragma unroll
  for (int s = 0; s < 3; ++s)
#pragma unroll
    for (int j = 0; j < 4; ++j) { float d = x[s][j] - mean; s2 += d * d; }
  float rs = rsqrtf(wave_sum(s2) * (1.0f / CC) + EPSF);
  if (lane == 0) { st[2 * row] = mean; st[2 * row + 1] = rs; }
}

// ---------------- LN + q_shift + token-mix, bf16 outputs ----------------
template <int NOUT>
__global__ __launch_bounds__(256) void k_mix(const float* __restrict__ xb,
                                             const float* __restrict__ st,
                                             const float* __restrict__ g,
                                             const float* __restrict__ b,
                                             const float* __restrict__ mk,
                                             const float* __restrict__ mv,
                                             const float* __restrict__ mr,
                                             bf16_t* __restrict__ ok,
                                             bf16_t* __restrict__ ov,
                                             bf16_t* __restrict__ orr, int M) {
  int tok = blockIdx.x * 4 + (threadIdx.x >> 6);
  if (tok >= M) return;
  int lane = threadIdx.x & 63;
  int t = tok % TB;
  int h = t / HWD, w = t % HWD;
  int nbr[4];
  nbr[0] = (w > 0)       ? tok - 1   : -1;
  nbr[1] = (w < HWD - 1) ? tok + 1   : -1;
  nbr[2] = (h > 0)       ? tok - HWD : -1;
  nbr[3] = (h < HWD - 1) ? tok + HWD : -1;
  float ms = st[2 * tok], rss = st[2 * tok + 1];
  const float* rp = xb + (size_t)tok * CC;
#pragma unroll
  for (int s = 0; s < 3; ++s) {
    int cc = s * 256 + lane * 4;
    int grp = cc / 192;
    int nb = nbr[grp];
    f32x4 xs = *(const f32x4*)(rp + cc);
    f32x4 xn = {0.f, 0.f, 0.f, 0.f};
    float mn = 0.f, rsn = 0.f;
    if (nb >= 0) {
      xn = *(const f32x4*)(xb + (size_t)nb * CC + cc);
      mn = st[2 * nb];
      rsn = st[2 * nb + 1];
    }
    f32x4 gg = *(const f32x4*)(g + cc);
    f32x4 bb = *(const f32x4*)(b + cc);
    f32x4 mk4 = *(const f32x4*)(mk + cc);
    f32x4 mr4 = *(const f32x4*)(mr + cc);
    f32x4 mv4 = {0.f, 0.f, 0.f, 0.f};
    if (NOUT == 3) mv4 = *(const f32x4*)(mv + cc);
    bf16x4 vk, vv, vr;
#pragma unroll
    for (int j = 0; j < 4; ++j) {
      float xi = (xs[j] - ms) * rss * gg[j] + bb[j];
      float xx = (nb >= 0) ? ((xn[j] - mn) * rsn * gg[j] + bb[j]) : 0.f;
      vk[j] = (bf16_t)(xi * mk4[j] + xx * (1.0f - mk4[j]));
      if (NOUT == 3) vv[j] = (bf16_t)(xi * mv4[j] + xx * (1.0f - mv4[j]));
      vr[j] = (bf16_t)(xi * mr4[j] + xx * (1.0f - mr4[j]));
    }
    *(bf16x4*)(ok + (size_t)tok * CC + cc) = vk;
    if (NOUT == 3) *(bf16x4*)(ov + (size_t)tok * CC + cc) = vv;
    *(bf16x4*)(orr + (size_t)tok * CC + cc) = vr;
  }
}

// ---------------- weight f32 (K,N) -> MFMA-fragment-packed bf16 ----------------
// Packed unit = 64 lanes x 16 B. Global unit index for tile (nt, kt), group gk:
//   unit = (nt*KT + kt)*16 + gk,  gk = g*2 + ks,  g = 0..7 (16-row group), ks = 0..1
// Lane l of unit holds B[n = nt*128 + g*16 + (l&15)][k = kt*64 + (ks*4+(l>>4))*8 .. +8]
// where B[n][k] = src[k*N + n]. A wave's 8 fragment loads are then contiguous
// 1-KB coalesced reads (the round-6 scatter problem eliminated).
__global__ __launch_bounds__(256) void k_pack(const float* __restrict__ src,
                                              bf16_t* __restrict__ dst, int K, int N) {
  int sid = blockIdx.x * 256 + threadIdx.x;          // one thread per 16B slot
  if (sid >= (K / 8) * N) return;
  int KT = K >> 6;
  int lane = sid & 63;
  int u = sid >> 6;
  int gk = u & 15;
  int ks = gk & 1, g = gk >> 1;
  int u2 = u >> 4;
  int kt = u2 % KT, nt = u2 / KT;
  int n = nt * 128 + g * 16 + (lane & 15);
  int k0 = kt * 64 + (ks * 4 + (lane >> 4)) * 8;
  bf16x8 o;
#pragma unroll
  for (int j = 0; j < 8; ++j) o[j] = (bf16_t)src[(size_t)(k0 + j) * N + n];
  *(bf16x8*)(dst + (size_t)sid * 8) = o;
}

// z-batched packer for the five 768x768 square weights
struct PackPair { const float* src; bf16_t* dst; };
struct PackBatch { PackPair p[5]; };
__global__ __launch_bounds__(256) void k_pack5(PackBatch pb) {
  PackPair pp = pb.p[blockIdx.z];
  int sid = blockIdx.x * 256 + threadIdx.x;
  if (sid >= 768 * 768 / 8) return;
  const int KT = 12;
  int lane = sid & 63;
  int u = sid >> 6;
  int gk = u & 15;
  int ks = gk & 1, g = gk >> 1;
  int u2 = u >> 4;
  int kt = u2 % KT, nt = u2 / KT;
  int n = nt * 128 + g * 16 + (lane & 15);
  int k0 = kt * 64 + (ks * 4 + (lane >> 4)) * 8;
  bf16x8 o;
#pragma unroll
  for (int j = 0; j < 8; ++j) o[j] = (bf16_t)pp.src[(size_t)(k0 + j) * 768 + n];
  *(bf16x8*)(pp.dst + (size_t)sid * 8) = o;
}

// ---------------- MFMA GEMM: 128x128, BK=64, A-in-LDS(dbuf) + packed-B-to-regs ----------------
// Round-7 chain cost: 2 barriers + B staged late (L2 latency waited at tail
// vmcnt(0)) + B's LDS roundtrip. This version: B is PRE-PACKED in fragment
// order (k_pack), so a wave's 8 B-fragment loads are coalesced 1-KB reads from
// the L2-resident weight, issued right after the MFMA that consumed the
// previous tile (~400cy before next use -> hidden). Single-buffered in regs
// (bB overwritten post-consumption): register liveness same as round 7.
// Per K-tile: {stageA(t+1)->alt buf | ds_read af | lgkm0 | vmcnt(4): B(t) done,
// A-stage in flight | MFMA | LOADB(t+1) | vmcnt(8): A(t+1) landed, B in flight
// | BAR}. ONE barrier, no B-LDS, LDS=32 KiB. launch_bounds(256,3): cap 170 >=
// ~136 unified (64 acc AGPR + ~72 VGPR) -> no spill (rounds 3/5 lesson).
enum { EPI_F32 = 0, EPI_SIG_BF16 = 1, EPI_RELU2_BF16 = 2, EPI_ADD = 3, EPI_GATE = 4 };

struct GemmArgs {
  const bf16_t* A;
  const bf16_t* B;      // fragment-packed (k_pack layout)
  void* C;
  const bf16_t* gate;   // EPI_GATE
  const float* resid;   // EPI_GATE
  int epi;
  int NT;               // N = NT*128; per-arg so independent gemms fuse in one launch
};
struct GemmBatch { GemmArgs a[3]; };

__global__ __launch_bounds__(256, 3) void k_gemm(GemmBatch batch, int M, int K, int Mt) {
  __shared__ __align__(16) ushort_t sA[2][128 * 64];
  int p = blockIdx.x, zi = 0;
  int nbk = Mt * batch.a[0].NT;
  while (p >= nbk && zi < 2) { p -= nbk; ++zi; nbk = Mt * batch.a[zi].NT; }
  GemmArgs ga = batch.a[zi];
  int NT = ga.NT;
  int N = NT << 7;
  int G = NT * 8, Mt8 = Mt & ~7;
  int m, n;
  if (p < Mt8 * NT) {
    int g = p / G;
    int r = p - g * G;
    m = g * 8 + (r & 7);
    n = r >> 3;
  } else {
    int r2 = p - Mt8 * NT;
    int rem = Mt - Mt8;
    m = Mt8 + r2 % rem;
    n = r2 / rem;
  }
  int bm = m << 7;
  int bn = n << 7;
  int tid = threadIdx.x;
  int wave = tid >> 6, lane = tid & 63;
  int fr = lane & 15, fq = lane >> 4, fr7 = fr & 7;
  int wm = (wave >> 1) * 64, wn = (wave & 1) * 64;
  int r0 = tid >> 3;          // 0..31: base row for A staging
  int pos = tid & 7;          // 16B chunk slot within the 128B LDS row
  int cs = pos ^ (r0 & 7);    // pre-swizzled source chunk ((r0+32j)&7 == r0&7)
  const bf16_t* Ab = ga.A + (size_t)bm * K;
  int KT = K >> 6;
  // packed-B base for this wave: unit = (n*KT + kt)*16 + (wave&1)*8 + i*2 + ks
  const bf16_t* Bp = ga.B + ((size_t)n * KT * 16 + (size_t)(wave & 1) * 8) * 512 + lane * 8;

  auto stageA = [&](int s, int kt) {
    int koff = kt * 64 + cs * 8;
#pragma unroll
    for (int j = 0; j < 4; ++j) {
      int row = j * 32 + r0;
      async_copy16(Ab + (size_t)row * K + koff, &sA[s][row * 64 + pos * 8]);
    }
  };

#define LOADB(T)                                                               \
  _Pragma("unroll") for (int i = 0; i < 4; ++i)                                \
  _Pragma("unroll") for (int ks = 0; ks < 2; ++ks)                             \
    bB[i][ks] = *(const bf16x8*)(Bp + ((size_t)(T) * 16 + i * 2 + ks) * 512);

  f32x4 acc[4][4] = {};
  bf16x8 bB[4][2];
  int niter = KT;
  stageA(0, 0);
  LOADB(0);
  SCHED_FENCE();
  asm volatile("s_waitcnt vmcnt(0)" ::: "memory");
  BAR();
  int buf = 0;
  for (int t = 0; t < niter; ++t) {
    // A(t) in sA[buf] (all-waves visible), B(t) in bB (this wave's regs).
    if (t + 1 < niter) stageA(buf ^ 1, t + 1);   // 4 loads, stay in flight
    SCHED_FENCE();
    bf16x8 af[4][2];
#pragma unroll
    for (int i = 0; i < 4; ++i) {
      int ra = wm + i * 16 + fr;
#pragma unroll
      for (int ks = 0; ks < 2; ++ks)
        af[i][ks] = *(const bf16x8*)&sA[buf][ra * 64 + (((ks * 4 + fq) ^ fr7) << 3)];
    }
    LGKM0();
    // B(t) (8 loads, oldest) done; A(t+1) (4 loads) may remain in flight.
    if (t + 1 < niter) asm volatile("s_waitcnt vmcnt(4)" ::: "memory");
    else               asm volatile("s_waitcnt vmcnt(0)" ::: "memory");
#pragma unroll
    for (int ks = 0; ks < 2; ++ks)
#pragma unroll
      for (int mi = 0; mi < 4; ++mi)
#pragma unroll
        for (int ni = 0; ni < 4; ++ni)
          acc[mi][ni] = __builtin_amdgcn_mfma_f32_16x16x32_bf16(af[mi][ks], bB[ni][ks], acc[mi][ni], 0, 0, 0);
    if (t + 1 < niter) {
      LOADB(t + 1);     // overwrite bB after consumption; lands during next tile's front
      SCHED_FENCE();
      asm volatile("s_waitcnt vmcnt(8)" ::: "memory");  // A(t+1) landed (B(t+1)'s 8 in flight)
      BAR();                                            // all waves' A(t+1) visible
    }
    buf ^= 1;
  }
  int epi = ga.epi;
#pragma unroll
  for (int mi = 0; mi < 4; ++mi) {
#pragma unroll
    for (int ni = 0; ni < 4; ++ni) {
#pragma unroll
      for (int r = 0; r < 4; ++r) {
        int grow = bm + wm + mi * 16 + fq * 4 + r;
        int gcol = bn + wn + ni * 16 + fr;
        size_t idx = (size_t)grow * N + gcol;
        float v = acc[mi][ni][r];
        if (epi == EPI_F32) {
          ((float*)ga.C)[idx] = v;
        } else if (epi == EPI_SIG_BF16) {
          ((bf16_t*)ga.C)[idx] = (bf16_t)(1.0f / (1.0f + __expf(-v)));
        } else if (epi == EPI_RELU2_BF16) {
          float tv = v > 0.f ? v : 0.f;
          ((bf16_t*)ga.C)[idx] = (bf16_t)(tv * tv);
        } else if (epi == EPI_ADD) {
          ((float*)ga.C)[idx] += v;
        } else {  // EPI_GATE: out = resid + sigmoid-gate * v
          ((float*)ga.C)[idx] = ga.resid[idx] + (float)ga.gate[idx] * v;
        }
      }
    }
  }
#undef LOADB
}

// ---------------- fused bidirectional WKV (bwd scan then fwd scan, same thread) ----------------
__global__ __launch_bounds__(256) void k_wkv(const float* __restrict__ k,
                                             const float* __restrict__ v,
                                             const float* __restrict__ decay,
                                             const float* __restrict__ first,
                                             bf16_t* __restrict__ ba,
                                             bf16_t* __restrict__ bb,
                                             bf16_t* __restrict__ r, int CB) {
  int idx = blockIdx.x * 256 + threadIdx.x;
  if (idx >= CB * CC) return;
  int c = idx % CC;
  size_t base = (size_t)(idx / CC) * TB * CC + c;
  float w = decay[c] * INV_T;
  float d = __expf(-w);
  float a = 0.f, bs = 0.f;
  for (int t = TB - 1; t >= 0; --t) {
    size_t p = base + (size_t)t * CC;
    ba[p] = (bf16_t)a;
    bb[p] = (bf16_t)bs;
    float ek = __expf(k[p]);
    a = d * (a + ek * v[p]);
    bs = d * (bs + ek);
  }
  float ew = __expf(w);
  float u = first[c] * INV_T;
  a = 0.f; bs = 0.f;
  for (int t = 0; t < TB; ++t) {
    size_t p = base + (size_t)t * CC;
    float kk = k[p], vv = v[p];
    float eu = __expf(u + kk);
    float num = ew * (a + (float)ba[p]) + eu * vv;
    float den = ew * (bs + (float)bb[p]) + eu;
    r[p] = (bf16_t)(num / den);
    float ek = __expf(kk);
    a = d * (a + ek * vv);
    bs = d * (bs + ek);
  }
}

// ---------------- LN(rwkv bf16) * sr -> bf16 ----------------
__global__ __launch_bounds__(256) void k_ln_mul(const bf16_t* __restrict__ in,
                                                const bf16_t* __restrict__ sr,
                                                const float* __restrict__ g,
                                                const float* __restrict__ b,
                                                bf16_t* __restrict__ out, int M) {
  int row = blockIdx.x * 4 + (threadIdx.x >> 6);
  if (row >= M) return;
  int lane = threadIdx.x & 63;
  const bf16_t* rp = in + (size_t)row * CC;
  int c0 = lane * 4;
  float x[12];
#pragma unroll
  for (int s = 0; s < 3; ++s) {
    bf16x4 t = *(const bf16x4*)(rp + s * 256 + c0);
#pragma unroll
    for (int j = 0; j < 4; ++j) x[s * 4 + j] = (float)t[j];
  }
  float sum = 0.f;
#pragma unroll
  for (int i = 0; i < 12; ++i) sum += x[i];
  float mean = wave_sum(sum) * (1.0f / CC);
  float s2 = 0.f;
#pragma unroll
  for (int i = 0; i < 12; ++i) { float d = x[i] - mean; s2 += d * d; }
  float rs = rsqrtf(wave_sum(s2) * (1.0f / CC) + EPSF);
#pragma unroll
  for (int s = 0; s < 3; ++s) {
    int cc = s * 256 + c0;
    f32x4 gg = *(const f32x4*)(g + cc);
    f32x4 bb = *(const f32x4*)(b + cc);
    bf16x4 s4 = *(const bf16x4*)(sr + (size_t)row * CC + cc);
    bf16x4 o;
#pragma unroll
    for (int j = 0; j < 4; ++j)
      o[j] = (bf16_t)(((x[s * 4 + j] - mean) * rs * gg[j] + bb[j]) * (float)s4[j]);
    *(bf16x4*)(out + (size_t)row * CC + cc) = o;
  }
}

// ---------------- LN over HID=3072 bf16 rows, IN-PLACE ----------------
__global__ __launch_bounds__(256) void k_ln_hid(bf16_t* __restrict__ io,
                                                const float* __restrict__ g,
                                                const float* __restrict__ b, int M) {
  int row = blockIdx.x * 4 + (threadIdx.x >> 6);
  if (row >= M) return;
  int lane = threadIdx.x & 63;
  bf16_t* rp = io + (size_t)row * HD;
  int c0 = lane * 8;
  bf16x8 x[6];
#pragma unroll
  for (int s = 0; s < 6; ++s) x[s] = *(const bf16x8*)(rp + s * 512 + c0);
  float sum = 0.f;
#pragma unroll
  for (int s = 0; s < 6; ++s)
#pragma unroll
    for (int j = 0; j < 8; ++j) sum += (float)x[s][j];
  float mean = wave_sum(sum) * (1.0f / HD);
  float s2 = 0.f;
#pragma unroll
  for (int s = 0; s < 6; ++s)
#pragma unroll
    for (int j = 0; j < 8; ++j) { float d = (float)x[s][j] - mean; s2 += d * d; }
  float rs = rsqrtf(wave_sum(s2) * (1.0f / HD) + EPSF);
#pragma unroll
  for (int s = 0; s < 6; ++s) {
    int cc = s * 512 + c0;
    f32x4 g0 = *(const f32x4*)(g + cc);
    f32x4 g1 = *(const f32x4*)(g + cc + 4);
    f32x4 b0 = *(const f32x4*)(b + cc);
    f32x4 b1 = *(const f32x4*)(b + cc + 4);
    bf16x8 o;
#pragma unroll
    for (int j = 0; j < 4; ++j) {
      o[j]     = (bf16_t)(((float)x[s][j]     - mean) * rs * g0[j] + b0[j]);
      o[j + 4] = (bf16_t)(((float)x[s][j + 4] - mean) * rs * g1[j] + b1[j]);
    }
    *(bf16x8*)(rp + cc) = o;
  }
}

// ---------------- host orchestration ----------------
struct Layout {
  size_t wk, wv, wr, wo, fk, fv, fr;
  size_t st, big, a16, b16, c16;
  size_t end;
};

static Layout make_layout(int CB) {
  Layout L;
  size_t off = 0;
  auto al = [&](size_t bytes) { size_t o = (off + 255) & ~(size_t)255; off = o + bytes; return o; };
  L.wk = al(589824ull * 2);
  L.wv = al(589824ull * 2);
  L.wr = al(589824ull * 2);
  L.wo = al(589824ull * 2);
  L.fk = al(2359296ull * 2);
  L.fv = al(2359296ull * 2);
  L.fr = al(589824ull * 2);
  size_t M = (size_t)CB * 196;
  size_t MC = M * 768;
  L.st  = al(M * 8);
  L.big = al(MC * 10);   // union: [K32|V32|SR16] vs [KFa]
  L.a16 = al(MC * 2);
  L.b16 = al(MC * 2);
  L.c16 = al(MC * 2);
  L.end = off;
  return L;
}

extern "C" void kernel_launch(void* const* d_in, const int* in_sizes, int n_in,
                              void* d_out, int out_size, void* d_ws, size_t ws_size,
                              hipStream_t stream) {
  const float* x      = (const float*)d_in[0];
  const float* ln0_g  = (const float*)d_in[1];
  const float* ln0_b  = (const float*)d_in[2];
  const float* ln1_g  = (const float*)d_in[3];
  const float* ln1_b  = (const float*)d_in[4];
  const float* ln2_g  = (const float*)d_in[5];
  const float* ln2_b  = (const float*)d_in[6];
  const float* amk    = (const float*)d_in[7];
  const float* amv    = (const float*)d_in[8];
  const float* amr    = (const float*)d_in[9];
  const float* adec   = (const float*)d_in[10];
  const float* afirst = (const float*)d_in[11];
  const float* aWk    = (const float*)d_in[12];
  const float* aWv    = (const float*)d_in[13];
  const float* aWr    = (const float*)d_in[14];
  const float* aWo    = (const float*)d_in[15];
  const float* akn_g  = (const float*)d_in[16];
  const float* akn_b  = (const float*)d_in[17];
  const float* fmk    = (const float*)d_in[18];
  const float* fmr    = (const float*)d_in[19];
  const float* fWk    = (const float*)d_in[20];
  const float* fWv    = (const float*)d_in[21];
  const float* fWr    = (const float*)d_in[22];
  const float* fkn_g  = (const float*)d_in[23];
  const float* fkn_b  = (const float*)d_in[24];

  int CB = 32;
  {
    const int cands[3] = {128, 64, 32};
    for (int i = 0; i < 3; ++i)
      if (make_layout(cands[i]).end <= ws_size) { CB = cands[i]; break; }
  }
  Layout L = make_layout(CB);
  int nchunk = 128 / CB;
  int M = CB * 196;
  size_t MC = (size_t)M * 768;

  uint8_t* ws = (uint8_t*)d_ws;
  bf16_t* WkT = (bf16_t*)(ws + L.wk);
  bf16_t* WvT = (bf16_t*)(ws + L.wv);
  bf16_t* WrT = (bf16_t*)(ws + L.wr);
  bf16_t* WoT = (bf16_t*)(ws + L.wo);
  bf16_t* FkT = (bf16_t*)(ws + L.fk);
  bf16_t* FvT = (bf16_t*)(ws + L.fv);
  bf16_t* FrT = (bf16_t*)(ws + L.fr);
  float*  ST  = (float*)(ws + L.st);
  uint8_t* big = ws + L.big;
  float*  K32 = (float*)(big);
  float*  V32 = (float*)(big + MC * 4);
  bf16_t* SR16 = (bf16_t*)(big + MC * 8);
  bf16_t* KFa = (bf16_t*)(big);            // M x 3072 bf16 (aliases K32+V32, dead by then)
  bf16_t* A16 = (bf16_t*)(ws + L.a16);
  bf16_t* B16 = (bf16_t*)(ws + L.b16);
  bf16_t* C16 = (bf16_t*)(ws + L.c16);
  // dead-window aliases: P/Q/R live in the xk/xv/xr buffers (consumed by QKV gemm)
  bf16_t* P16 = A16;
  bf16_t* Q16 = B16;
  bf16_t* R16 = C16;

  {
    PackBatch pb;
    pb.p[0] = {aWk, WkT}; pb.p[1] = {aWv, WvT}; pb.p[2] = {aWr, WrT};
    pb.p[3] = {aWo, WoT}; pb.p[4] = {fWr, FrT};
    k_pack5<<<dim3(288, 1, 5), 256, 0, stream>>>(pb);
  }
  k_pack<<<1152, 256, 0, stream>>>(fWk, FkT, 768, 3072);
  k_pack<<<1152, 256, 0, stream>>>(fWv, FvT, 3072, 768);

  int rowb = M / 4;
  int Mt = M / 128;
  int wkvb = (CB * 768) / 256;

  for (int ch = 0; ch < nchunk; ++ch) {
    const float* xin = x + (size_t)ch * MC;
    float* XB = (float*)d_out + (size_t)ch * MC;   // residual stream lives in d_out

    // ---- attention half ----
    k_ln0<<<rowb, 256, 0, stream>>>(xin, ln0_g, ln0_b, XB, ST, M);
    k_mix<3><<<rowb, 256, 0, stream>>>(XB, ST, ln1_g, ln1_b, amk, amv, amr, A16, B16, C16, M);
    {
      GemmBatch gb{};
      gb.a[0] = {A16, WkT, K32, nullptr, nullptr, EPI_F32, 6};
      gb.a[1] = {B16, WvT, V32, nullptr, nullptr, EPI_F32, 6};
      gb.a[2] = {C16, WrT, SR16, nullptr, nullptr, EPI_SIG_BF16, 6};
      k_gemm<<<dim3(Mt * 18), 256, 0, stream>>>(gb, M, 768, Mt);
    }
    // A16/B16/C16 (xk/xv/xr) are dead now -> reuse as P16/Q16/R16
    k_wkv<<<wkvb, 256, 0, stream>>>(K32, V32, adec, afirst, P16, Q16, R16, CB);
    k_ln_mul<<<rowb, 256, 0, stream>>>(R16, SR16, akn_g, akn_b, A16, M);
    {
      GemmBatch gb{};
      gb.a[0] = {A16, WoT, XB, nullptr, nullptr, EPI_ADD, 6};
      k_gemm<<<dim3(Mt * 6), 256, 0, stream>>>(gb, M, 768, Mt);
    }

    // ---- ffn half ----
    k_stats<<<rowb, 256, 0, stream>>>(XB, ST, M);
    k_mix<2><<<rowb, 256, 0, stream>>>(XB, ST, ln2_g, ln2_b, fmk, nullptr, fmr, A16, nullptr, C16, M);
    {
      // FFN-K (NT=24) and Wr (NT=6) are independent: fuse into one launch
      GemmBatch gb{};
      gb.a[0] = {A16, FkT, KFa, nullptr, nullptr, EPI_RELU2_BF16, 24};
      gb.a[1] = {C16, FrT, B16, nullptr, nullptr, EPI_SIG_BF16, 6};
      k_gemm<<<dim3(Mt * 30), 256, 0, stream>>>(gb, M, 768, Mt);
    }
    k_ln_hid<<<rowb, 256, 0, stream>>>(KFa, fkn_g, fkn_b, M);   // in-place
    {
      GemmBatch gb{};
      gb.a[0] = {KFa, FvT, XB, B16, XB, EPI_GATE, 6};
      k_gemm<<<dim3(Mt * 6), 256, 0, stream>>>(gb, M, 3072, Mt);
    }
  }
}

// Round 9
// 1085.916 us; speedup vs baseline: 1.0517x; 1.0517x over previous
//
#include <hip/hip_runtime.h>
#include <stdint.h>

typedef __bf16 bf16_t;
typedef __bf16 bf16x8 __attribute__((ext_vector_type(8)));
typedef __bf16 bf16x4 __attribute__((ext_vector_type(4)));
typedef float f32x4 __attribute__((ext_vector_type(4)));
typedef unsigned short ushort_t;

#define CC 768
#define HD 3072
#define TB 196
#define HWD 14
#define EPSF 1e-5f
#define INV_T (1.0f/196.0f)

// ---------------- helpers ----------------
__device__ __forceinline__ float wave_sum(float v) {
#pragma unroll
  for (int off = 32; off > 0; off >>= 1) v += __shfl_xor(v, off, 64);
  return v;
}

__device__ __forceinline__ void async_copy16(const void* g, void* l) {
  typedef __attribute__((address_space(3))) uint32_t lds_u32;
  typedef __attribute__((address_space(1))) const uint32_t glb_u32;
  glb_u32* gp = (glb_u32*)(uintptr_t)g;
  lds_u32* lp = (lds_u32*)(uint32_t)(uintptr_t)l;
  __builtin_amdgcn_global_load_lds(gp, lp, 16, 0, 0);
}

#define SCHED_FENCE() asm volatile("" ::: "memory")
#define BAR() asm volatile("s_barrier" ::: "memory")
#define LGKM0() asm volatile("s_waitcnt lgkmcnt(0)" ::: "memory")

// ---------------- LN0 (normalized row to XB + stats of output row) ----------------
__global__ __launch_bounds__(256) void k_ln0(const float* __restrict__ in,
                                             const float* __restrict__ g,
                                             const float* __restrict__ b,
                                             float* __restrict__ out,
                                             float* __restrict__ st, int M) {
  int row = blockIdx.x * 4 + (threadIdx.x >> 6);
  if (row >= M) return;
  int lane = threadIdx.x & 63;
  const float* rp = in + (size_t)row * CC;
  int c0 = lane * 4;
  f32x4 x[3];
#pragma unroll
  for (int s = 0; s < 3; ++s) x[s] = *(const f32x4*)(rp + s * 256 + c0);
  float sum = 0.f;
#pragma unroll
  for (int s = 0; s < 3; ++s)
#pragma unroll
    for (int j = 0; j < 4; ++j) sum += x[s][j];
  float mean = wave_sum(sum) * (1.0f / CC);
  float s2 = 0.f;
#pragma unroll
  for (int s = 0; s < 3; ++s)
#pragma unroll
    for (int j = 0; j < 4; ++j) { float d = x[s][j] - mean; s2 += d * d; }
  float rs = rsqrtf(wave_sum(s2) * (1.0f / CC) + EPSF);
  float* op = out + (size_t)row * CC;
  f32x4 o[3];
  float sum2 = 0.f;
#pragma unroll
  for (int s = 0; s < 3; ++s) {
    int cc = s * 256 + c0;
    f32x4 gg = *(const f32x4*)(g + cc);
    f32x4 bb = *(const f32x4*)(b + cc);
#pragma unroll
    for (int j = 0; j < 4; ++j) {
      o[s][j] = (x[s][j] - mean) * rs * gg[j] + bb[j];
      sum2 += o[s][j];
    }
    *(f32x4*)(op + cc) = o[s];
  }
  float mean2 = wave_sum(sum2) * (1.0f / CC);
  float q2 = 0.f;
#pragma unroll
  for (int s = 0; s < 3; ++s)
#pragma unroll
    for (int j = 0; j < 4; ++j) { float d = o[s][j] - mean2; q2 += d * d; }
  float rs2 = rsqrtf(wave_sum(q2) * (1.0f / CC) + EPSF);
  if (lane == 0) { st[2 * row] = mean2; st[2 * row + 1] = rs2; }
}

// ---------------- per-row mean/rstd ----------------
__global__ __launch_bounds__(256) void k_stats(const float* __restrict__ in,
                                               float* __restrict__ st, int M) {
  int row = blockIdx.x * 4 + (threadIdx.x >> 6);
  if (row >= M) return;
  int lane = threadIdx.x & 63;
  const float* rp = in + (size_t)row * CC;
  int c0 = lane * 4;
  f32x4 x[3];
#pragma unroll
  for (int s = 0; s < 3; ++s) x[s] = *(const f32x4*)(rp + s * 256 + c0);
  float sum = 0.f;
#pragma unroll
  for (int s = 0; s < 3; ++s)
#pragma unroll
    for (int j = 0; j < 4; ++j) sum += x[s][j];
  float mean = wave_sum(sum) * (1.0f / CC);
  float s2 = 0.f;
#pragma unroll
  for (int s = 0; s < 3; ++s)
#pragma unroll
    for (int j = 0; j < 4; ++j) { float d = x[s][j] - mean; s2 += d * d; }
  float rs = rsqrtf(wave_sum(s2) * (1.0f / CC) + EPSF);
  if (lane == 0) { st[2 * row] = mean; st[2 * row + 1] = rs; }
}

// ---------------- LN + q_shift + token-mix, bf16 outputs ----------------
template <int NOUT>
__global__ __launch_bounds__(256) void k_mix(const float* __restrict__ xb,
                                             const float* __restrict__ st,
                                             const float* __restrict__ g,
                                             const float* __restrict__ b,
                                             const float* __restrict__ mk,
                                             const float* __restrict__ mv,
                                             const float* __restrict__ mr,
                                             bf16_t* __restrict__ ok,
                                             bf16_t* __restrict__ ov,
                                             bf16_t* __restrict__ orr, int M) {
  int tok = blockIdx.x * 4 + (threadIdx.x >> 6);
  if (tok >= M) return;
  int lane = threadIdx.x & 63;
  int t = tok % TB;
  int h = t / HWD, w = t % HWD;
  int nbr[4];
  nbr[0] = (w > 0)       ? tok - 1   : -1;
  nbr[1] = (w < HWD - 1) ? tok + 1   : -1;
  nbr[2] = (h > 0)       ? tok - HWD : -1;
  nbr[3] = (h < HWD - 1) ? tok + HWD : -1;
  float ms = st[2 * tok], rss = st[2 * tok + 1];
  const float* rp = xb + (size_t)tok * CC;
#pragma unroll
  for (int s = 0; s < 3; ++s) {
    int cc = s * 256 + lane * 4;
    int grp = cc / 192;
    int nb = nbr[grp];
    f32x4 xs = *(const f32x4*)(rp + cc);
    f32x4 xn = {0.f, 0.f, 0.f, 0.f};
    float mn = 0.f, rsn = 0.f;
    if (nb >= 0) {
      xn = *(const f32x4*)(xb + (size_t)nb * CC + cc);
      mn = st[2 * nb];
      rsn = st[2 * nb + 1];
    }
    f32x4 gg = *(const f32x4*)(g + cc);
    f32x4 bb = *(const f32x4*)(b + cc);
    f32x4 mk4 = *(const f32x4*)(mk + cc);
    f32x4 mr4 = *(const f32x4*)(mr + cc);
    f32x4 mv4 = {0.f, 0.f, 0.f, 0.f};
    if (NOUT == 3) mv4 = *(const f32x4*)(mv + cc);
    bf16x4 vk, vv, vr;
#pragma unroll
    for (int j = 0; j < 4; ++j) {
      float xi = (xs[j] - ms) * rss * gg[j] + bb[j];
      float xx = (nb >= 0) ? ((xn[j] - mn) * rsn * gg[j] + bb[j]) : 0.f;
      vk[j] = (bf16_t)(xi * mk4[j] + xx * (1.0f - mk4[j]));
      if (NOUT == 3) vv[j] = (bf16_t)(xi * mv4[j] + xx * (1.0f - mv4[j]));
      vr[j] = (bf16_t)(xi * mr4[j] + xx * (1.0f - mr4[j]));
    }
    *(bf16x4*)(ok + (size_t)tok * CC + cc) = vk;
    if (NOUT == 3) *(bf16x4*)(ov + (size_t)tok * CC + cc) = vv;
    *(bf16x4*)(orr + (size_t)tok * CC + cc) = vr;
  }
}

// ---------------- weight f32 (K,N) -> bf16 transposed (N,K) ----------------
__global__ __launch_bounds__(256) void k_tcvt(const float* __restrict__ src,
                                              bf16_t* __restrict__ dst, int K, int N) {
  __shared__ float tile[32][33];
  int tx = threadIdx.x & 31;
  int ty = threadIdx.x >> 5;
  int n0 = blockIdx.x * 32, k0 = blockIdx.y * 32;
#pragma unroll
  for (int i = 0; i < 4; ++i)
    tile[ty + 8 * i][tx] = src[(size_t)(k0 + ty + 8 * i) * N + n0 + tx];
  __syncthreads();
#pragma unroll
  for (int i = 0; i < 4; ++i)
    dst[(size_t)(n0 + ty + 8 * i) * K + k0 + tx] = (bf16_t)tile[tx][ty + 8 * i];
}

// z-batched 768x768 transposes (one launch for the 5 square weights)
struct TcvtPair { const float* src; bf16_t* dst; };
struct TcvtBatch { TcvtPair p[5]; };
__global__ __launch_bounds__(256) void k_tcvt5(TcvtBatch tb) {
  __shared__ float tile[32][33];
  TcvtPair pp = tb.p[blockIdx.z];
  int tx = threadIdx.x & 31;
  int ty = threadIdx.x >> 5;
  int n0 = blockIdx.x * 32, k0 = blockIdx.y * 32;
#pragma unroll
  for (int i = 0; i < 4; ++i)
    tile[ty + 8 * i][tx] = pp.src[(size_t)(k0 + ty + 8 * i) * 768 + n0 + tx];
  __syncthreads();
#pragma unroll
  for (int i = 0; i < 4; ++i)
    pp.dst[(size_t)(n0 + ty + 8 * i) * 768 + k0 + tx] = (bf16_t)tile[tx][ty + 8 * i];
}

// ---------------- MFMA GEMM: 128x128, BK=64, A-dbuf + B-single, 48 KiB, 3 blocks/CU ----------------
// Round-7 structure (session best, 1075 us). Per-CU K-tile cost ~1100 cy ==
// the LDS-BW floor of this 4-wave geometry (96 KB LDS traffic/tile at ~90 B/cy);
// B-out-of-LDS variants (rounds 5/6/8) all measured worse. Do not touch.
enum { EPI_F32 = 0, EPI_SIG_BF16 = 1, EPI_RELU2_BF16 = 2, EPI_ADD = 3, EPI_GATE = 4 };

struct GemmArgs {
  const bf16_t* A;
  const bf16_t* B;
  void* C;
  const bf16_t* gate;   // EPI_GATE
  const float* resid;   // EPI_GATE
  int epi;
  int NT;               // N = NT*128; per-arg so independent gemms fuse in one launch
};
struct GemmBatch { GemmArgs a[3]; };

__global__ __launch_bounds__(256, 3) void k_gemm(GemmBatch batch, int M, int K, int Mt) {
  __shared__ __align__(16) ushort_t sA[2][128 * 64];
  __shared__ __align__(16) ushort_t sB[128 * 64];
  int p = blockIdx.x, zi = 0;
  int nbk = Mt * batch.a[0].NT;
  while (p >= nbk && zi < 2) { p -= nbk; ++zi; nbk = Mt * batch.a[zi].NT; }
  GemmArgs ga = batch.a[zi];
  int NT = ga.NT;
  int N = NT << 7;
  int G = NT * 8, Mt8 = Mt & ~7;
  int m, n;
  if (p < Mt8 * NT) {
    int g = p / G;
    int r = p - g * G;
    m = g * 8 + (r & 7);
    n = r >> 3;
  } else {
    int r2 = p - Mt8 * NT;
    int rem = Mt - Mt8;
    m = Mt8 + r2 % rem;
    n = r2 / rem;
  }
  int bm = m << 7, bn = n << 7;
  int tid = threadIdx.x;
  int wave = tid >> 6, lane = tid & 63;
  int fr = lane & 15, fq = lane >> 4, fr7 = fr & 7;
  int wm = (wave >> 1) * 64, wn = (wave & 1) * 64;
  int r0 = tid >> 3;          // 0..31: base row for staging
  int pos = tid & 7;          // 16B chunk slot within the 128B LDS row
  int cs = pos ^ (r0 & 7);    // pre-swizzled source chunk ((r0+32j)&7 == r0&7)
  const bf16_t* Ab = ga.A + (size_t)bm * K;
  const bf16_t* Bb = ga.B + (size_t)bn * K;

  auto stageA = [&](int s, int kt) {
    int koff = kt * 64 + cs * 8;
#pragma unroll
    for (int j = 0; j < 4; ++j) {
      int row = j * 32 + r0;
      async_copy16(Ab + (size_t)row * K + koff, &sA[s][row * 64 + pos * 8]);
    }
  };
  auto stageB = [&](int kt) {
    int koff = kt * 64 + cs * 8;
#pragma unroll
    for (int j = 0; j < 4; ++j) {
      int row = j * 32 + r0;
      async_copy16(Bb + (size_t)row * K + koff, &sB[row * 64 + pos * 8]);
    }
  };

  f32x4 acc[4][4] = {};
  int niter = K >> 6;
  stageA(0, 0);
  stageB(0);
  SCHED_FENCE();
  asm volatile("s_waitcnt vmcnt(0)" ::: "memory");
  BAR();
  int buf = 0;
  for (int t = 0; t < niter; ++t) {
    // A(t) in sA[buf], B(t) in sB, both landed (tail vmcnt+BAR of prev iter).
    if (t + 1 < niter) stageA(buf ^ 1, t + 1);   // double-buffered: race-free early issue
    SCHED_FENCE();
    bf16x8 bfv[4][2];
#pragma unroll
    for (int i = 0; i < 4; ++i) {
      int rb = wn + i * 16 + fr;
#pragma unroll
      for (int ks = 0; ks < 2; ++ks)
        bfv[i][ks] = *(const bf16x8*)&sB[rb * 64 + (((ks * 4 + fq) ^ fr7) << 3)];
    }
    LGKM0();            // own B reads done
    BAR();              // ALL waves' B reads done -> sB safe to overwrite
    if (t + 1 < niter) stageB(t + 1);
    SCHED_FENCE();
    bf16x8 af[4][2];
#pragma unroll
    for (int i = 0; i < 4; ++i) {
      int ra = wm + i * 16 + fr;
#pragma unroll
      for (int ks = 0; ks < 2; ++ks)
        af[i][ks] = *(const bf16x8*)&sA[buf][ra * 64 + (((ks * 4 + fq) ^ fr7) << 3)];
    }
    LGKM0();
#pragma unroll
    for (int ks = 0; ks < 2; ++ks)
#pragma unroll
      for (int mi = 0; mi < 4; ++mi)
#pragma unroll
        for (int ni = 0; ni < 4; ++ni)
          acc[mi][ni] = __builtin_amdgcn_mfma_f32_16x16x32_bf16(af[mi][ks], bfv[ni][ks], acc[mi][ni], 0, 0, 0);
    asm volatile("s_waitcnt vmcnt(0)" ::: "memory");  // A(t+1), B(t+1) landed
    BAR();
    buf ^= 1;
  }
  int epi = ga.epi;
#pragma unroll
  for (int mi = 0; mi < 4; ++mi) {
#pragma unroll
    for (int ni = 0; ni < 4; ++ni) {
#pragma unroll
      for (int r = 0; r < 4; ++r) {
        int grow = bm + wm + mi * 16 + fq * 4 + r;
        int gcol = bn + wn + ni * 16 + fr;
        size_t idx = (size_t)grow * N + gcol;
        float v = acc[mi][ni][r];
        if (epi == EPI_F32) {
          ((float*)ga.C)[idx] = v;
        } else if (epi == EPI_SIG_BF16) {
          ((bf16_t*)ga.C)[idx] = (bf16_t)(1.0f / (1.0f + __expf(-v)));
        } else if (epi == EPI_RELU2_BF16) {
          float tv = v > 0.f ? v : 0.f;
          ((bf16_t*)ga.C)[idx] = (bf16_t)(tv * tv);
        } else if (epi == EPI_ADD) {
          ((float*)ga.C)[idx] += v;
        } else {  // EPI_GATE: out = resid + sigmoid-gate * v
          ((float*)ga.C)[idx] = ga.resid[idx] + (float)ga.gate[idx] * v;
        }
      }
    }
  }
}

// ---------------- bidirectional WKV scans ----------------
// 64-thread blocks: B*C = 98304 lanes -> 1536 blocks (vs 384 at 256-thread),
// evenly 6 blocks/CU across 256 CUs. At 256-thread the 384 blocks split 2/1
// across CUs -> structural 2x load imbalance on a latency-bound scan.
__global__ __launch_bounds__(64) void k_wkv_bwd(const float* __restrict__ k,
                                                const float* __restrict__ v,
                                                const float* __restrict__ decay,
                                                bf16_t* __restrict__ ba,
                                                bf16_t* __restrict__ bb, int CB) {
  int idx = blockIdx.x * 64 + threadIdx.x;
  if (idx >= CB * CC) return;
  int c = idx % CC;
  size_t base = (size_t)(idx / CC) * TB * CC + c;
  float w = decay[c] * INV_T;
  float d = __expf(-w);
  float a = 0.f, bs = 0.f;
  for (int t = TB - 1; t >= 0; --t) {
    size_t p = base + (size_t)t * CC;
    ba[p] = (bf16_t)a;
    bb[p] = (bf16_t)bs;
    float ek = __expf(k[p]);
    a = d * (a + ek * v[p]);
    bs = d * (bs + ek);
  }
}

__global__ __launch_bounds__(64) void k_wkv_fwd(const float* __restrict__ k,
                                                const float* __restrict__ v,
                                                const float* __restrict__ decay,
                                                const float* __restrict__ first,
                                                const bf16_t* __restrict__ ba,
                                                const bf16_t* __restrict__ bb,
                                                bf16_t* __restrict__ r, int CB) {
  int idx = blockIdx.x * 64 + threadIdx.x;
  if (idx >= CB * CC) return;
  int c = idx % CC;
  size_t base = (size_t)(idx / CC) * TB * CC + c;
  float w = decay[c] * INV_T;
  float d = __expf(-w);
  float ew = __expf(w);
  float u = first[c] * INV_T;
  float a = 0.f, bs = 0.f;
  for (int t = 0; t < TB; ++t) {
    size_t p = base + (size_t)t * CC;
    float kk = k[p], vv = v[p];
    float eu = __expf(u + kk);
    float num = ew * (a + (float)ba[p]) + eu * vv;
    float den = ew * (bs + (float)bb[p]) + eu;
    r[p] = (bf16_t)(num / den);
    float ek = __expf(kk);
    a = d * (a + ek * vv);
    bs = d * (bs + ek);
  }
}

// ---------------- LN(rwkv bf16) * sr -> bf16 ----------------
__global__ __launch_bounds__(256) void k_ln_mul(const bf16_t* __restrict__ in,
                                                const bf16_t* __restrict__ sr,
                                                const float* __restrict__ g,
                                                const float* __restrict__ b,
                                                bf16_t* __restrict__ out, int M) {
  int row = blockIdx.x * 4 + (threadIdx.x >> 6);
  if (row >= M) return;
  int lane = threadIdx.x & 63;
  const bf16_t* rp = in + (size_t)row * CC;
  int c0 = lane * 4;
  float x[12];
#pragma unroll
  for (int s = 0; s < 3; ++s) {
    bf16x4 t = *(const bf16x4*)(rp + s * 256 + c0);
#pragma unroll
    for (int j = 0; j < 4; ++j) x[s * 4 + j] = (float)t[j];
  }
  float sum = 0.f;
#pragma unroll
  for (int i = 0; i < 12; ++i) sum += x[i];
  float mean = wave_sum(sum) * (1.0f / CC);
  float s2 = 0.f;
#pragma unroll
  for (int i = 0; i < 12; ++i) { float d = x[i] - mean; s2 += d * d; }
  float rs = rsqrtf(wave_sum(s2) * (1.0f / CC) + EPSF);
#pragma unroll
  for (int s = 0; s < 3; ++s) {
    int cc = s * 256 + c0;
    f32x4 gg = *(const f32x4*)(g + cc);
    f32x4 bb = *(const f32x4*)(b + cc);
    bf16x4 s4 = *(const bf16x4*)(sr + (size_t)row * CC + cc);
    bf16x4 o;
#pragma unroll
    for (int j = 0; j < 4; ++j)
      o[j] = (bf16_t)(((x[s * 4 + j] - mean) * rs * gg[j] + bb[j]) * (float)s4[j]);
    *(bf16x4*)(out + (size_t)row * CC + cc) = o;
  }
}

// ---------------- LN over HID=3072 bf16 rows, IN-PLACE ----------------
__global__ __launch_bounds__(256) void k_ln_hid(bf16_t* __restrict__ io,
                                                const float* __restrict__ g,
                                                const float* __restrict__ b, int M) {
  int row = blockIdx.x * 4 + (threadIdx.x >> 6);
  if (row >= M) return;
  int lane = threadIdx.x & 63;
  bf16_t* rp = io + (size_t)row * HD;
  int c0 = lane * 8;
  bf16x8 x[6];
#pragma unroll
  for (int s = 0; s < 6; ++s) x[s] = *(const bf16x8*)(rp + s * 512 + c0);
  float sum = 0.f;
#pragma unroll
  for (int s = 0; s < 6; ++s)
#pragma unroll
    for (int j = 0; j < 8; ++j) sum += (float)x[s][j];
  float mean = wave_sum(sum) * (1.0f / HD);
  float s2 = 0.f;
#pragma unroll
  for (int s = 0; s < 6; ++s)
#pragma unroll
    for (int j = 0; j < 8; ++j) { float d = (float)x[s][j] - mean; s2 += d * d; }
  float rs = rsqrtf(wave_sum(s2) * (1.0f / HD) + EPSF);
#pragma unroll
  for (int s = 0; s < 6; ++s) {
    int cc = s * 512 + c0;
    f32x4 g0 = *(const f32x4*)(g + cc);
    f32x4 g1 = *(const f32x4*)(g + cc + 4);
    f32x4 b0 = *(const f32x4*)(b + cc);
    f32x4 b1 = *(const f32x4*)(b + cc + 4);
    bf16x8 o;
#pragma unroll
    for (int j = 0; j < 4; ++j) {
      o[j]     = (bf16_t)(((float)x[s][j]     - mean) * rs * g0[j] + b0[j]);
      o[j + 4] = (bf16_t)(((float)x[s][j + 4] - mean) * rs * g1[j] + b1[j]);
    }
    *(bf16x8*)(rp + cc) = o;
  }
}

// ---------------- host orchestration ----------------
struct Layout {
  size_t wk, wv, wr, wo, fk, fv, fr;
  size_t st, big, a16, b16, c16;
  size_t end;
};

static Layout make_layout(int CB) {
  Layout L;
  size_t off = 0;
  auto al = [&](size_t bytes) { size_t o = (off + 255) & ~(size_t)255; off = o + bytes; return o; };
  L.wk = al(589824ull * 2);
  L.wv = al(589824ull * 2);
  L.wr = al(589824ull * 2);
  L.wo = al(589824ull * 2);
  L.fk = al(2359296ull * 2);
  L.fv = al(2359296ull * 2);
  L.fr = al(589824ull * 2);
  size_t M = (size_t)CB * 196;
  size_t MC = M * 768;
  L.st  = al(M * 8);
  L.big = al(MC * 10);   // union: [K32|V32|SR16] vs [KFa]
  L.a16 = al(MC * 2);
  L.b16 = al(MC * 2);
  L.c16 = al(MC * 2);
  L.end = off;
  return L;
}

extern "C" void kernel_launch(void* const* d_in, const int* in_sizes, int n_in,
                              void* d_out, int out_size, void* d_ws, size_t ws_size,
                              hipStream_t stream) {
  const float* x      = (const float*)d_in[0];
  const float* ln0_g  = (const float*)d_in[1];
  const float* ln0_b  = (const float*)d_in[2];
  const float* ln1_g  = (const float*)d_in[3];
  const float* ln1_b  = (const float*)d_in[4];
  const float* ln2_g  = (const float*)d_in[5];
  const float* ln2_b  = (const float*)d_in[6];
  const float* amk    = (const float*)d_in[7];
  const float* amv    = (const float*)d_in[8];
  const float* amr    = (const float*)d_in[9];
  const float* adec   = (const float*)d_in[10];
  const float* afirst = (const float*)d_in[11];
  const float* aWk    = (const float*)d_in[12];
  const float* aWv    = (const float*)d_in[13];
  const float* aWr    = (const float*)d_in[14];
  const float* aWo    = (const float*)d_in[15];
  const float* akn_g  = (const float*)d_in[16];
  const float* akn_b  = (const float*)d_in[17];
  const float* fmk    = (const float*)d_in[18];
  const float* fmr    = (const float*)d_in[19];
  const float* fWk    = (const float*)d_in[20];
  const float* fWv    = (const float*)d_in[21];
  const float* fWr    = (const float*)d_in[22];
  const float* fkn_g  = (const float*)d_in[23];
  const float* fkn_b  = (const float*)d_in[24];

  int CB = 32;
  {
    const int cands[3] = {128, 64, 32};
    for (int i = 0; i < 3; ++i)
      if (make_layout(cands[i]).end <= ws_size) { CB = cands[i]; break; }
  }
  Layout L = make_layout(CB);
  int nchunk = 128 / CB;
  int M = CB * 196;
  size_t MC = (size_t)M * 768;

  uint8_t* ws = (uint8_t*)d_ws;
  bf16_t* WkT = (bf16_t*)(ws + L.wk);
  bf16_t* WvT = (bf16_t*)(ws + L.wv);
  bf16_t* WrT = (bf16_t*)(ws + L.wr);
  bf16_t* WoT = (bf16_t*)(ws + L.wo);
  bf16_t* FkT = (bf16_t*)(ws + L.fk);
  bf16_t* FvT = (bf16_t*)(ws + L.fv);
  bf16_t* FrT = (bf16_t*)(ws + L.fr);
  float*  ST  = (float*)(ws + L.st);
  uint8_t* big = ws + L.big;
  float*  K32 = (float*)(big);
  float*  V32 = (float*)(big + MC * 4);
  bf16_t* SR16 = (bf16_t*)(big + MC * 8);
  bf16_t* KFa = (bf16_t*)(big);            // M x 3072 bf16 (aliases K32+V32, dead by then)
  bf16_t* A16 = (bf16_t*)(ws + L.a16);
  bf16_t* B16 = (bf16_t*)(ws + L.b16);
  bf16_t* C16 = (bf16_t*)(ws + L.c16);
  // dead-window aliases: P/Q/R live in the xk/xv/xr buffers (consumed by QKV gemm)
  bf16_t* P16 = A16;
  bf16_t* Q16 = B16;
  bf16_t* R16 = C16;

  {
    TcvtBatch tb;
    tb.p[0] = {aWk, WkT}; tb.p[1] = {aWv, WvT}; tb.p[2] = {aWr, WrT};
    tb.p[3] = {aWo, WoT}; tb.p[4] = {fWr, FrT};
    k_tcvt5<<<dim3(24, 24, 5), 256, 0, stream>>>(tb);
  }
  k_tcvt<<<dim3(96, 24), 256, 0, stream>>>(fWk, FkT, 768, 3072);
  k_tcvt<<<dim3(24, 96), 256, 0, stream>>>(fWv, FvT, 3072, 768);

  int rowb = M / 4;
  int Mt = M / 128;
  int wkvb = (CB * 768) / 64;   // 64-thread blocks for CU-balanced scan

  for (int ch = 0; ch < nchunk; ++ch) {
    const float* xin = x + (size_t)ch * MC;
    float* XB = (float*)d_out + (size_t)ch * MC;   // residual stream lives in d_out

    // ---- attention half ----
    k_ln0<<<rowb, 256, 0, stream>>>(xin, ln0_g, ln0_b, XB, ST, M);
    k_mix<3><<<rowb, 256, 0, stream>>>(XB, ST, ln1_g, ln1_b, amk, amv, amr, A16, B16, C16, M);
    {
      GemmBatch gb{};
      gb.a[0] = {A16, WkT, K32, nullptr, nullptr, EPI_F32, 6};
      gb.a[1] = {B16, WvT, V32, nullptr, nullptr, EPI_F32, 6};
      gb.a[2] = {C16, WrT, SR16, nullptr, nullptr, EPI_SIG_BF16, 6};
      k_gemm<<<dim3(Mt * 18), 256, 0, stream>>>(gb, M, 768, Mt);
    }
    // A16/B16/C16 (xk/xv/xr) are dead now -> reuse as P16/Q16/R16
    k_wkv_bwd<<<wkvb, 64, 0, stream>>>(K32, V32, adec, P16, Q16, CB);
    k_wkv_fwd<<<wkvb, 64, 0, stream>>>(K32, V32, adec, afirst, P16, Q16, R16, CB);
    k_ln_mul<<<rowb, 256, 0, stream>>>(R16, SR16, akn_g, akn_b, A16, M);
    {
      GemmBatch gb{};
      gb.a[0] = {A16, WoT, XB, nullptr, nullptr, EPI_ADD, 6};
      k_gemm<<<dim3(Mt * 6), 256, 0, stream>>>(gb, M, 768, Mt);
    }

    // ---- ffn half ----
    k_stats<<<rowb, 256, 0, stream>>>(XB, ST, M);
    k_mix<2><<<rowb, 256, 0, stream>>>(XB, ST, ln2_g, ln2_b, fmk, nullptr, fmr, A16, nullptr, C16, M);
    {
      // FFN-K (NT=24) and Wr (NT=6) are independent: fuse into one launch
      GemmBatch gb{};
      gb.a[0] = {A16, FkT, KFa, nullptr, nullptr, EPI_RELU2_BF16, 24};
      gb.a[1] = {C16, FrT, B16, nullptr, nullptr, EPI_SIG_BF16, 6};
      k_gemm<<<dim3(Mt * 30), 256, 0, stream>>>(gb, M, 768, Mt);
    }
    k_ln_hid<<<rowb, 256, 0, stream>>>(KFa, fkn_g, fkn_b, M);   // in-place
    {
      GemmBatch gb{};
      gb.a[0] = {KFa, FvT, XB, B16, XB, EPI_GATE, 6};
      k_gemm<<<dim3(Mt * 6), 256, 0, stream>>>(gb, M, 3072, Mt);
    }
  }
}

// Round 10
// 1082.711 us; speedup vs baseline: 1.0548x; 1.0030x over previous
//
#include <hip/hip_runtime.h>
#include <stdint.h>

typedef __bf16 bf16_t;
typedef __bf16 bf16x8 __attribute__((ext_vector_type(8)));
typedef __bf16 bf16x4 __attribute__((ext_vector_type(4)));
typedef float f32x4 __attribute__((ext_vector_type(4)));
typedef unsigned short ushort_t;

#define CC 768
#define HD 3072
#define TB 196
#define HWD 14
#define EPSF 1e-5f
#define INV_T (1.0f/196.0f)

// ---------------- helpers ----------------
__device__ __forceinline__ float wave_sum(float v) {
#pragma unroll
  for (int off = 32; off > 0; off >>= 1) v += __shfl_xor(v, off, 64);
  return v;
}

__device__ __forceinline__ void async_copy16(const void* g, void* l) {
  typedef __attribute__((address_space(3))) uint32_t lds_u32;
  typedef __attribute__((address_space(1))) const uint32_t glb_u32;
  glb_u32* gp = (glb_u32*)(uintptr_t)g;
  lds_u32* lp = (lds_u32*)(uint32_t)(uintptr_t)l;
  __builtin_amdgcn_global_load_lds(gp, lp, 16, 0, 0);
}

#define SCHED_FENCE() asm volatile("" ::: "memory")
#define BAR() asm volatile("s_barrier" ::: "memory")
#define LGKM0() asm volatile("s_waitcnt lgkmcnt(0)" ::: "memory")

// ---------------- LN0 (normalized row to XB + stats of output row) ----------------
__global__ __launch_bounds__(256) void k_ln0(const float* __restrict__ in,
                                             const float* __restrict__ g,
                                             const float* __restrict__ b,
                                             float* __restrict__ out,
                                             float* __restrict__ st, int M) {
  int row = blockIdx.x * 4 + (threadIdx.x >> 6);
  if (row >= M) return;
  int lane = threadIdx.x & 63;
  const float* rp = in + (size_t)row * CC;
  int c0 = lane * 4;
  f32x4 x[3];
#pragma unroll
  for (int s = 0; s < 3; ++s) x[s] = *(const f32x4*)(rp + s * 256 + c0);
  float sum = 0.f;
#pragma unroll
  for (int s = 0; s < 3; ++s)
#pragma unroll
    for (int j = 0; j < 4; ++j) sum += x[s][j];
  float mean = wave_sum(sum) * (1.0f / CC);
  float s2 = 0.f;
#pragma unroll
  for (int s = 0; s < 3; ++s)
#pragma unroll
    for (int j = 0; j < 4; ++j) { float d = x[s][j] - mean; s2 += d * d; }
  float rs = rsqrtf(wave_sum(s2) * (1.0f / CC) + EPSF);
  float* op = out + (size_t)row * CC;
  f32x4 o[3];
  float sum2 = 0.f;
#pragma unroll
  for (int s = 0; s < 3; ++s) {
    int cc = s * 256 + c0;
    f32x4 gg = *(const f32x4*)(g + cc);
    f32x4 bb = *(const f32x4*)(b + cc);
#pragma unroll
    for (int j = 0; j < 4; ++j) {
      o[s][j] = (x[s][j] - mean) * rs * gg[j] + bb[j];
      sum2 += o[s][j];
    }
    *(f32x4*)(op + cc) = o[s];
  }
  float mean2 = wave_sum(sum2) * (1.0f / CC);
  float q2 = 0.f;
#pragma unroll
  for (int s = 0; s < 3; ++s)
#pragma unroll
    for (int j = 0; j < 4; ++j) { float d = o[s][j] - mean2; q2 += d * d; }
  float rs2 = rsqrtf(wave_sum(q2) * (1.0f / CC) + EPSF);
  if (lane == 0) { st[2 * row] = mean2; st[2 * row + 1] = rs2; }
}

// ---------------- per-row mean/rstd ----------------
__global__ __launch_bounds__(256) void k_stats(const float* __restrict__ in,
                                               float* __restrict__ st, int M) {
  int row = blockIdx.x * 4 + (threadIdx.x >> 6);
  if (row >= M) return;
  int lane = threadIdx.x & 63;
  const float* rp = in + (size_t)row * CC;
  int c0 = lane * 4;
  f32x4 x[3];
#pragma unroll
  for (int s = 0; s < 3; ++s) x[s] = *(const f32x4*)(rp + s * 256 + c0);
  float sum = 0.f;
#pragma unroll
  for (int s = 0; s < 3; ++s)
#pragma unroll
    for (int j = 0; j < 4; ++j) sum += x[s][j];
  float mean = wave_sum(sum) * (1.0f / CC);
  float s2 = 0.f;
#pragma unroll
  for (int s = 0; s < 3; ++s)
#pragma unroll
    for (int j = 0; j < 4; ++j) { float d = x[s][j] - mean; s2 += d * d; }
  float rs = rsqrtf(wave_sum(s2) * (1.0f / CC) + EPSF);
  if (lane == 0) { st[2 * row] = mean; st[2 * row + 1] = rs; }
}

// ---------------- LN + q_shift + token-mix, bf16 outputs ----------------
template <int NOUT>
__global__ __launch_bounds__(256) void k_mix(const float* __restrict__ xb,
                                             const float* __restrict__ st,
                                             const float* __restrict__ g,
                                             const float* __restrict__ b,
                                             const float* __restrict__ mk,
                                             const float* __restrict__ mv,
                                             const float* __restrict__ mr,
                                             bf16_t* __restrict__ ok,
                                             bf16_t* __restrict__ ov,
                                             bf16_t* __restrict__ orr, int M) {
  int tok = blockIdx.x * 4 + (threadIdx.x >> 6);
  if (tok >= M) return;
  int lane = threadIdx.x & 63;
  int t = tok % TB;
  int h = t / HWD, w = t % HWD;
  int nbr[4];
  nbr[0] = (w > 0)       ? tok - 1   : -1;
  nbr[1] = (w < HWD - 1) ? tok + 1   : -1;
  nbr[2] = (h > 0)       ? tok - HWD : -1;
  nbr[3] = (h < HWD - 1) ? tok + HWD : -1;
  float ms = st[2 * tok], rss = st[2 * tok + 1];
  const float* rp = xb + (size_t)tok * CC;
#pragma unroll
  for (int s = 0; s < 3; ++s) {
    int cc = s * 256 + lane * 4;
    int grp = cc / 192;
    int nb = nbr[grp];
    f32x4 xs = *(const f32x4*)(rp + cc);
    f32x4 xn = {0.f, 0.f, 0.f, 0.f};
    float mn = 0.f, rsn = 0.f;
    if (nb >= 0) {
      xn = *(const f32x4*)(xb + (size_t)nb * CC + cc);
      mn = st[2 * nb];
      rsn = st[2 * nb + 1];
    }
    f32x4 gg = *(const f32x4*)(g + cc);
    f32x4 bb = *(const f32x4*)(b + cc);
    f32x4 mk4 = *(const f32x4*)(mk + cc);
    f32x4 mr4 = *(const f32x4*)(mr + cc);
    f32x4 mv4 = {0.f, 0.f, 0.f, 0.f};
    if (NOUT == 3) mv4 = *(const f32x4*)(mv + cc);
    bf16x4 vk, vv, vr;
#pragma unroll
    for (int j = 0; j < 4; ++j) {
      float xi = (xs[j] - ms) * rss * gg[j] + bb[j];
      float xx = (nb >= 0) ? ((xn[j] - mn) * rsn * gg[j] + bb[j]) : 0.f;
      vk[j] = (bf16_t)(xi * mk4[j] + xx * (1.0f - mk4[j]));
      if (NOUT == 3) vv[j] = (bf16_t)(xi * mv4[j] + xx * (1.0f - mv4[j]));
      vr[j] = (bf16_t)(xi * mr4[j] + xx * (1.0f - mr4[j]));
    }
    *(bf16x4*)(ok + (size_t)tok * CC + cc) = vk;
    if (NOUT == 3) *(bf16x4*)(ov + (size_t)tok * CC + cc) = vv;
    *(bf16x4*)(orr + (size_t)tok * CC + cc) = vr;
  }
}

// ---------------- weight f32 (K,N) -> bf16 transposed (N,K) ----------------
__global__ __launch_bounds__(256) void k_tcvt(const float* __restrict__ src,
                                              bf16_t* __restrict__ dst, int K, int N) {
  __shared__ float tile[32][33];
  int tx = threadIdx.x & 31;
  int ty = threadIdx.x >> 5;
  int n0 = blockIdx.x * 32, k0 = blockIdx.y * 32;
#pragma unroll
  for (int i = 0; i < 4; ++i)
    tile[ty + 8 * i][tx] = src[(size_t)(k0 + ty + 8 * i) * N + n0 + tx];
  __syncthreads();
#pragma unroll
  for (int i = 0; i < 4; ++i)
    dst[(size_t)(n0 + ty + 8 * i) * K + k0 + tx] = (bf16_t)tile[tx][ty + 8 * i];
}

// z-batched 768x768 transposes (one launch for the 5 square weights)
struct TcvtPair { const float* src; bf16_t* dst; };
struct TcvtBatch { TcvtPair p[5]; };
__global__ __launch_bounds__(256) void k_tcvt5(TcvtBatch tb) {
  __shared__ float tile[32][33];
  TcvtPair pp = tb.p[blockIdx.z];
  int tx = threadIdx.x & 31;
  int ty = threadIdx.x >> 5;
  int n0 = blockIdx.x * 32, k0 = blockIdx.y * 32;
#pragma unroll
  for (int i = 0; i < 4; ++i)
    tile[ty + 8 * i][tx] = pp.src[(size_t)(k0 + ty + 8 * i) * 768 + n0 + tx];
  __syncthreads();
#pragma unroll
  for (int i = 0; i < 4; ++i)
    pp.dst[(size_t)(n0 + ty + 8 * i) * 768 + k0 + tx] = (bf16_t)tile[tx][ty + 8 * i];
}

// ---------------- MFMA GEMM: 128x128, BK=64, A-dbuf + B-single, 48 KiB, 3 blocks/CU ----------------
// Round-7 structure (session best). Per-CU K-tile cost ~1100 cy == the LDS-BW
// floor of this 4-wave geometry (96 KB LDS traffic/tile at ~90 B/cy);
// B-out-of-LDS variants (rounds 5/6/8) all measured worse. FROZEN.
enum { EPI_F32 = 0, EPI_SIG_BF16 = 1, EPI_RELU2_BF16 = 2, EPI_ADD = 3, EPI_GATE = 4 };

struct GemmArgs {
  const bf16_t* A;
  const bf16_t* B;
  void* C;
  const bf16_t* gate;   // EPI_GATE
  const float* resid;   // EPI_GATE
  int epi;
  int NT;               // N = NT*128; per-arg so independent gemms fuse in one launch
};
struct GemmBatch { GemmArgs a[3]; };

__global__ __launch_bounds__(256, 3) void k_gemm(GemmBatch batch, int M, int K, int Mt) {
  __shared__ __align__(16) ushort_t sA[2][128 * 64];
  __shared__ __align__(16) ushort_t sB[128 * 64];
  int p = blockIdx.x, zi = 0;
  int nbk = Mt * batch.a[0].NT;
  while (p >= nbk && zi < 2) { p -= nbk; ++zi; nbk = Mt * batch.a[zi].NT; }
  GemmArgs ga = batch.a[zi];
  int NT = ga.NT;
  int N = NT << 7;
  int G = NT * 8, Mt8 = Mt & ~7;
  int m, n;
  if (p < Mt8 * NT) {
    int g = p / G;
    int r = p - g * G;
    m = g * 8 + (r & 7);
    n = r >> 3;
  } else {
    int r2 = p - Mt8 * NT;
    int rem = Mt - Mt8;
    m = Mt8 + r2 % rem;
    n = r2 / rem;
  }
  int bm = m << 7, bn = n << 7;
  int tid = threadIdx.x;
  int wave = tid >> 6, lane = tid & 63;
  int fr = lane & 15, fq = lane >> 4, fr7 = fr & 7;
  int wm = (wave >> 1) * 64, wn = (wave & 1) * 64;
  int r0 = tid >> 3;          // 0..31: base row for staging
  int pos = tid & 7;          // 16B chunk slot within the 128B LDS row
  int cs = pos ^ (r0 & 7);    // pre-swizzled source chunk ((r0+32j)&7 == r0&7)
  const bf16_t* Ab = ga.A + (size_t)bm * K;
  const bf16_t* Bb = ga.B + (size_t)bn * K;

  auto stageA = [&](int s, int kt) {
    int koff = kt * 64 + cs * 8;
#pragma unroll
    for (int j = 0; j < 4; ++j) {
      int row = j * 32 + r0;
      async_copy16(Ab + (size_t)row * K + koff, &sA[s][row * 64 + pos * 8]);
    }
  };
  auto stageB = [&](int kt) {
    int koff = kt * 64 + cs * 8;
#pragma unroll
    for (int j = 0; j < 4; ++j) {
      int row = j * 32 + r0;
      async_copy16(Bb + (size_t)row * K + koff, &sB[row * 64 + pos * 8]);
    }
  };

  f32x4 acc[4][4] = {};
  int niter = K >> 6;
  stageA(0, 0);
  stageB(0);
  SCHED_FENCE();
  asm volatile("s_waitcnt vmcnt(0)" ::: "memory");
  BAR();
  int buf = 0;
  for (int t = 0; t < niter; ++t) {
    // A(t) in sA[buf], B(t) in sB, both landed (tail vmcnt+BAR of prev iter).
    if (t + 1 < niter) stageA(buf ^ 1, t + 1);   // double-buffered: race-free early issue
    SCHED_FENCE();
    bf16x8 bfv[4][2];
#pragma unroll
    for (int i = 0; i < 4; ++i) {
      int rb = wn + i * 16 + fr;
#pragma unroll
      for (int ks = 0; ks < 2; ++ks)
        bfv[i][ks] = *(const bf16x8*)&sB[rb * 64 + (((ks * 4 + fq) ^ fr7) << 3)];
    }
    LGKM0();            // own B reads done
    BAR();              // ALL waves' B reads done -> sB safe to overwrite
    if (t + 1 < niter) stageB(t + 1);
    SCHED_FENCE();
    bf16x8 af[4][2];
#pragma unroll
    for (int i = 0; i < 4; ++i) {
      int ra = wm + i * 16 + fr;
#pragma unroll
      for (int ks = 0; ks < 2; ++ks)
        af[i][ks] = *(const bf16x8*)&sA[buf][ra * 64 + (((ks * 4 + fq) ^ fr7) << 3)];
    }
    LGKM0();
#pragma unroll
    for (int ks = 0; ks < 2; ++ks)
#pragma unroll
      for (int mi = 0; mi < 4; ++mi)
#pragma unroll
        for (int ni = 0; ni < 4; ++ni)
          acc[mi][ni] = __builtin_amdgcn_mfma_f32_16x16x32_bf16(af[mi][ks], bfv[ni][ks], acc[mi][ni], 0, 0, 0);
    asm volatile("s_waitcnt vmcnt(0)" ::: "memory");  // A(t+1), B(t+1) landed
    BAR();
    buf ^= 1;
  }
  int epi = ga.epi;
#pragma unroll
  for (int mi = 0; mi < 4; ++mi) {
#pragma unroll
    for (int ni = 0; ni < 4; ++ni) {
#pragma unroll
      for (int r = 0; r < 4; ++r) {
        int grow = bm + wm + mi * 16 + fq * 4 + r;
        int gcol = bn + wn + ni * 16 + fr;
        size_t idx = (size_t)grow * N + gcol;
        float v = acc[mi][ni][r];
        if (epi == EPI_F32) {
          ((float*)ga.C)[idx] = v;
        } else if (epi == EPI_SIG_BF16) {
          ((bf16_t*)ga.C)[idx] = (bf16_t)(1.0f / (1.0f + __expf(-v)));
        } else if (epi == EPI_RELU2_BF16) {
          float tv = v > 0.f ? v : 0.f;
          ((bf16_t*)ga.C)[idx] = (bf16_t)(tv * tv);
        } else if (epi == EPI_ADD) {
          ((float*)ga.C)[idx] += v;
        } else {  // EPI_GATE: out = resid + sigmoid-gate * v
          ((float*)ga.C)[idx] = ga.resid[idx] + (float)ga.gate[idx] * v;
        }
      }
    }
  }
}

// ---------------- bidirectional WKV scans ----------------
// Latency-bound diagnosis (rounds 0-9): 196 DEPENDENT iterations, each
// stalling ~600cy on a fresh load with only ~1.5 waves/SIMD resident.
// Fix (G7 ILP): 14-wide load batching (TB = 14x14) + distance-1 group
// prefetch - one memory latency amortizes over 14 scan steps, and the next
// group's 28 loads are issued before the current group's compute. All
// register-array indexing is compile-time (rule #20: unrolled j only).
#define WG 14

__global__ __launch_bounds__(64) void k_wkv_bwd(const float* __restrict__ k,
                                                const float* __restrict__ v,
                                                const float* __restrict__ decay,
                                                bf16_t* __restrict__ ba,
                                                bf16_t* __restrict__ bb, int CB) {
  int idx = blockIdx.x * 64 + threadIdx.x;
  if (idx >= CB * CC) return;
  int c = idx % CC;
  size_t base = (size_t)(idx / CC) * TB * CC + c;
  float w = decay[c] * INV_T;
  float d = __expf(-w);
  float a = 0.f, bs = 0.f;
  float ck[WG], cv[WG], nk[WG], nv[WG];
  int tg = TB - WG;
#pragma unroll
  for (int j = 0; j < WG; ++j) {
    size_t p = base + (size_t)(tg + j) * CC;
    ck[j] = k[p]; cv[j] = v[p];
  }
  for (; tg >= 0; tg -= WG) {
    int tn = tg - WG;
    if (tn >= 0) {
#pragma unroll
      for (int j = 0; j < WG; ++j) {
        size_t p = base + (size_t)(tn + j) * CC;
        nk[j] = k[p]; nv[j] = v[p];
      }
    }
#pragma unroll
    for (int j = WG - 1; j >= 0; --j) {
      size_t p = base + (size_t)(tg + j) * CC;
      ba[p] = (bf16_t)a;
      bb[p] = (bf16_t)bs;
      float ek = __expf(ck[j]);
      a = d * (a + ek * cv[j]);
      bs = d * (bs + ek);
    }
#pragma unroll
    for (int j = 0; j < WG; ++j) { ck[j] = nk[j]; cv[j] = nv[j]; }
  }
}

__global__ __launch_bounds__(64) void k_wkv_fwd(const float* __restrict__ k,
                                                const float* __restrict__ v,
                                                const float* __restrict__ decay,
                                                const float* __restrict__ first,
                                                const bf16_t* __restrict__ ba,
                                                const bf16_t* __restrict__ bb,
                                                bf16_t* __restrict__ r, int CB) {
  int idx = blockIdx.x * 64 + threadIdx.x;
  if (idx >= CB * CC) return;
  int c = idx % CC;
  size_t base = (size_t)(idx / CC) * TB * CC + c;
  float w = decay[c] * INV_T;
  float d = __expf(-w);
  float ew = __expf(w);
  float euc = __expf(first[c] * INV_T);   // exp(u); eu = euc * exp(k) (1 exp/step)
  float a = 0.f, bs = 0.f;
  float ck[WG], cv[WG], pa[WG], pb[WG];
  float nk[WG], nv[WG], na[WG], nb[WG];
#pragma unroll
  for (int j = 0; j < WG; ++j) {
    size_t p = base + (size_t)j * CC;
    ck[j] = k[p]; cv[j] = v[p];
    pa[j] = (float)ba[p]; pb[j] = (float)bb[p];
  }
  for (int tg = 0; tg < TB; tg += WG) {
    int tn = tg + WG;
    if (tn < TB) {
#pragma unroll
      for (int j = 0; j < WG; ++j) {
        size_t p = base + (size_t)(tn + j) * CC;
        nk[j] = k[p]; nv[j] = v[p];
        na[j] = (float)ba[p]; nb[j] = (float)bb[p];
      }
    }
#pragma unroll
    for (int j = 0; j < WG; ++j) {
      size_t p = base + (size_t)(tg + j) * CC;
      float ek = __expf(ck[j]);
      float eu = euc * ek;
      float num = ew * (a + pa[j]) + eu * cv[j];
      float den = ew * (bs + pb[j]) + eu;
      r[p] = (bf16_t)(num / den);
      a = d * (a + ek * cv[j]);
      bs = d * (bs + ek);
    }
#pragma unroll
    for (int j = 0; j < WG; ++j) { ck[j] = nk[j]; cv[j] = nv[j]; pa[j] = na[j]; pb[j] = nb[j]; }
  }
}

// ---------------- LN(rwkv bf16) * sr -> bf16 ----------------
__global__ __launch_bounds__(256) void k_ln_mul(const bf16_t* __restrict__ in,
                                                const bf16_t* __restrict__ sr,
                                                const float* __restrict__ g,
                                                const float* __restrict__ b,
                                                bf16_t* __restrict__ out, int M) {
  int row = blockIdx.x * 4 + (threadIdx.x >> 6);
  if (row >= M) return;
  int lane = threadIdx.x & 63;
  const bf16_t* rp = in + (size_t)row * CC;
  int c0 = lane * 4;
  float x[12];
#pragma unroll
  for (int s = 0; s < 3; ++s) {
    bf16x4 t = *(const bf16x4*)(rp + s * 256 + c0);
#pragma unroll
    for (int j = 0; j < 4; ++j) x[s * 4 + j] = (float)t[j];
  }
  float sum = 0.f;
#pragma unroll
  for (int i = 0; i < 12; ++i) sum += x[i];
  float mean = wave_sum(sum) * (1.0f / CC);
  float s2 = 0.f;
#pragma unroll
  for (int i = 0; i < 12; ++i) { float d = x[i] - mean; s2 += d * d; }
  float rs = rsqrtf(wave_sum(s2) * (1.0f / CC) + EPSF);
#pragma unroll
  for (int s = 0; s < 3; ++s) {
    int cc = s * 256 + c0;
    f32x4 gg = *(const f32x4*)(g + cc);
    f32x4 bb = *(const f32x4*)(b + cc);
    bf16x4 s4 = *(const bf16x4*)(sr + (size_t)row * CC + cc);
    bf16x4 o;
#pragma unroll
    for (int j = 0; j < 4; ++j)
      o[j] = (bf16_t)(((x[s * 4 + j] - mean) * rs * gg[j] + bb[j]) * (float)s4[j]);
    *(bf16x4*)(out + (size_t)row * CC + cc) = o;
  }
}

// ---------------- LN over HID=3072 bf16 rows, IN-PLACE ----------------
__global__ __launch_bounds__(256) void k_ln_hid(bf16_t* __restrict__ io,
                                                const float* __restrict__ g,
                                                const float* __restrict__ b, int M) {
  int row = blockIdx.x * 4 + (threadIdx.x >> 6);
  if (row >= M) return;
  int lane = threadIdx.x & 63;
  bf16_t* rp = io + (size_t)row * HD;
  int c0 = lane * 8;
  bf16x8 x[6];
#pragma unroll
  for (int s = 0; s < 6; ++s) x[s] = *(const bf16x8*)(rp + s * 512 + c0);
  float sum = 0.f;
#pragma unroll
  for (int s = 0; s < 6; ++s)
#pragma unroll
    for (int j = 0; j < 8; ++j) sum += (float)x[s][j];
  float mean = wave_sum(sum) * (1.0f / HD);
  float s2 = 0.f;
#pragma unroll
  for (int s = 0; s < 6; ++s)
#pragma unroll
    for (int j = 0; j < 8; ++j) { float d = (float)x[s][j] - mean; s2 += d * d; }
  float rs = rsqrtf(wave_sum(s2) * (1.0f / HD) + EPSF);
#pragma unroll
  for (int s = 0; s < 6; ++s) {
    int cc = s * 512 + c0;
    f32x4 g0 = *(const f32x4*)(g + cc);
    f32x4 g1 = *(const f32x4*)(g + cc + 4);
    f32x4 b0 = *(const f32x4*)(b + cc);
    f32x4 b1 = *(const f32x4*)(b + cc + 4);
    bf16x8 o;
#pragma unroll
    for (int j = 0; j < 4; ++j) {
      o[j]     = (bf16_t)(((float)x[s][j]     - mean) * rs * g0[j] + b0[j]);
      o[j + 4] = (bf16_t)(((float)x[s][j + 4] - mean) * rs * g1[j] + b1[j]);
    }
    *(bf16x8*)(rp + cc) = o;
  }
}

// ---------------- host orchestration ----------------
struct Layout {
  size_t wk, wv, wr, wo, fk, fv, fr;
  size_t st, big, a16, b16, c16;
  size_t end;
};

static Layout make_layout(int CB) {
  Layout L;
  size_t off = 0;
  auto al = [&](size_t bytes) { size_t o = (off + 255) & ~(size_t)255; off = o + bytes; return o; };
  L.wk = al(589824ull * 2);
  L.wv = al(589824ull * 2);
  L.wr = al(589824ull * 2);
  L.wo = al(589824ull * 2);
  L.fk = al(2359296ull * 2);
  L.fv = al(2359296ull * 2);
  L.fr = al(589824ull * 2);
  size_t M = (size_t)CB * 196;
  size_t MC = M * 768;
  L.st  = al(M * 8);
  L.big = al(MC * 10);   // union: [K32|V32|SR16] vs [KFa]
  L.a16 = al(MC * 2);
  L.b16 = al(MC * 2);
  L.c16 = al(MC * 2);
  L.end = off;
  return L;
}

extern "C" void kernel_launch(void* const* d_in, const int* in_sizes, int n_in,
                              void* d_out, int out_size, void* d_ws, size_t ws_size,
                              hipStream_t stream) {
  const float* x      = (const float*)d_in[0];
  const float* ln0_g  = (const float*)d_in[1];
  const float* ln0_b  = (const float*)d_in[2];
  const float* ln1_g  = (const float*)d_in[3];
  const float* ln1_b  = (const float*)d_in[4];
  const float* ln2_g  = (const float*)d_in[5];
  const float* ln2_b  = (const float*)d_in[6];
  const float* amk    = (const float*)d_in[7];
  const float* amv    = (const float*)d_in[8];
  const float* amr    = (const float*)d_in[9];
  const float* adec   = (const float*)d_in[10];
  const float* afirst = (const float*)d_in[11];
  const float* aWk    = (const float*)d_in[12];
  const float* aWv    = (const float*)d_in[13];
  const float* aWr    = (const float*)d_in[14];
  const float* aWo    = (const float*)d_in[15];
  const float* akn_g  = (const float*)d_in[16];
  const float* akn_b  = (const float*)d_in[17];
  const float* fmk    = (const float*)d_in[18];
  const float* fmr    = (const float*)d_in[19];
  const float* fWk    = (const float*)d_in[20];
  const float* fWv    = (const float*)d_in[21];
  const float* fWr    = (const float*)d_in[22];
  const float* fkn_g  = (const float*)d_in[23];
  const float* fkn_b  = (const float*)d_in[24];

  int CB = 32;
  {
    const int cands[3] = {128, 64, 32};
    for (int i = 0; i < 3; ++i)
      if (make_layout(cands[i]).end <= ws_size) { CB = cands[i]; break; }
  }
  Layout L = make_layout(CB);
  int nchunk = 128 / CB;
  int M = CB * 196;
  size_t MC = (size_t)M * 768;

  uint8_t* ws = (uint8_t*)d_ws;
  bf16_t* WkT = (bf16_t*)(ws + L.wk);
  bf16_t* WvT = (bf16_t*)(ws + L.wv);
  bf16_t* WrT = (bf16_t*)(ws + L.wr);
  bf16_t* WoT = (bf16_t*)(ws + L.wo);
  bf16_t* FkT = (bf16_t*)(ws + L.fk);
  bf16_t* FvT = (bf16_t*)(ws + L.fv);
  bf16_t* FrT = (bf16_t*)(ws + L.fr);
  float*  ST  = (float*)(ws + L.st);
  uint8_t* big = ws + L.big;
  float*  K32 = (float*)(big);
  float*  V32 = (float*)(big + MC * 4);
  bf16_t* SR16 = (bf16_t*)(big + MC * 8);
  bf16_t* KFa = (bf16_t*)(big);            // M x 3072 bf16 (aliases K32+V32, dead by then)
  bf16_t* A16 = (bf16_t*)(ws + L.a16);
  bf16_t* B16 = (bf16_t*)(ws + L.b16);
  bf16_t* C16 = (bf16_t*)(ws + L.c16);
  // dead-window aliases: P/Q/R live in the xk/xv/xr buffers (consumed by QKV gemm)
  bf16_t* P16 = A16;
  bf16_t* Q16 = B16;
  bf16_t* R16 = C16;

  {
    TcvtBatch tb;
    tb.p[0] = {aWk, WkT}; tb.p[1] = {aWv, WvT}; tb.p[2] = {aWr, WrT};
    tb.p[3] = {aWo, WoT}; tb.p[4] = {fWr, FrT};
    k_tcvt5<<<dim3(24, 24, 5), 256, 0, stream>>>(tb);
  }
  k_tcvt<<<dim3(96, 24), 256, 0, stream>>>(fWk, FkT, 768, 3072);
  k_tcvt<<<dim3(24, 96), 256, 0, stream>>>(fWv, FvT, 3072, 768);

  int rowb = M / 4;
  int Mt = M / 128;
  int wkvb = (CB * 768) / 64;   // 64-thread blocks: balanced 6 blocks/CU

  for (int ch = 0; ch < nchunk; ++ch) {
    const float* xin = x + (size_t)ch * MC;
    float* XB = (float*)d_out + (size_t)ch * MC;   // residual stream lives in d_out

    // ---- attention half ----
    k_ln0<<<rowb, 256, 0, stream>>>(xin, ln0_g, ln0_b, XB, ST, M);
    k_mix<3><<<rowb, 256, 0, stream>>>(XB, ST, ln1_g, ln1_b, amk, amv, amr, A16, B16, C16, M);
    {
      GemmBatch gb{};
      gb.a[0] = {A16, WkT, K32, nullptr, nullptr, EPI_F32, 6};
      gb.a[1] = {B16, WvT, V32, nullptr, nullptr, EPI_F32, 6};
      gb.a[2] = {C16, WrT, SR16, nullptr, nullptr, EPI_SIG_BF16, 6};
      k_gemm<<<dim3(Mt * 18), 256, 0, stream>>>(gb, M, 768, Mt);
    }
    // A16/B16/C16 (xk/xv/xr) are dead now -> reuse as P16/Q16/R16
    k_wkv_bwd<<<wkvb, 64, 0, stream>>>(K32, V32, adec, P16, Q16, CB);
    k_wkv_fwd<<<wkvb, 64, 0, stream>>>(K32, V32, adec, afirst, P16, Q16, R16, CB);
    k_ln_mul<<<rowb, 256, 0, stream>>>(R16, SR16, akn_g, akn_b, A16, M);
    {
      GemmBatch gb{};
      gb.a[0] = {A16, WoT, XB, nullptr, nullptr, EPI_ADD, 6};
      k_gemm<<<dim3(Mt * 6), 256, 0, stream>>>(gb, M, 768, Mt);
    }

    // ---- ffn half ----
    k_stats<<<rowb, 256, 0, stream>>>(XB, ST, M);
    k_mix<2><<<rowb, 256, 0, stream>>>(XB, ST, ln2_g, ln2_b, fmk, nullptr, fmr, A16, nullptr, C16, M);
    {
      // FFN-K (NT=24) and Wr (NT=6) are independent: fuse into one launch
      GemmBatch gb{};
      gb.a[0] = {A16, FkT, KFa, nullptr, nullptr, EPI_RELU2_BF16, 24};
      gb.a[1] = {C16, FrT, B16, nullptr, nullptr, EPI_SIG_BF16, 6};
      k_gemm<<<dim3(Mt * 30), 256, 0, stream>>>(gb, M, 768, Mt);
    }
    k_ln_hid<<<rowb, 256, 0, stream>>>(KFa, fkn_g, fkn_b, M);   // in-place
    {
      GemmBatch gb{};
      gb.a[0] = {KFa, FvT, XB, B16, XB, EPI_GATE, 6};
      k_gemm<<<dim3(Mt * 6), 256, 0, stream>>>(gb, M, 3072, Mt);
    }
  }
}

// Round 11
// 1022.642 us; speedup vs baseline: 1.1168x; 1.0587x over previous
//
#include <hip/hip_runtime.h>
#include <stdint.h>

typedef __bf16 bf16_t;
typedef __bf16 bf16x8 __attribute__((ext_vector_type(8)));
typedef __bf16 bf16x4 __attribute__((ext_vector_type(4)));
typedef float f32x4 __attribute__((ext_vector_type(4)));
typedef unsigned short ushort_t;

#define CC 768
#define HD 3072
#define TB 196
#define HWD 14
#define EPSF 1e-5f
#define INV_T (1.0f/196.0f)

// ---------------- helpers ----------------
__device__ __forceinline__ float wave_sum(float v) {
#pragma unroll
  for (int off = 32; off > 0; off >>= 1) v += __shfl_xor(v, off, 64);
  return v;
}

__device__ __forceinline__ void async_copy16(const void* g, void* l) {
  typedef __attribute__((address_space(3))) uint32_t lds_u32;
  typedef __attribute__((address_space(1))) const uint32_t glb_u32;
  glb_u32* gp = (glb_u32*)(uintptr_t)g;
  lds_u32* lp = (lds_u32*)(uint32_t)(uintptr_t)l;
  __builtin_amdgcn_global_load_lds(gp, lp, 16, 0, 0);
}

#define SCHED_FENCE() asm volatile("" ::: "memory")
#define BAR() asm volatile("s_barrier" ::: "memory")
#define LGKM0() asm volatile("s_waitcnt lgkmcnt(0)" ::: "memory")

// ---------------- LN0 (normalized row to XB + stats of output row) ----------------
__global__ __launch_bounds__(256) void k_ln0(const float* __restrict__ in,
                                             const float* __restrict__ g,
                                             const float* __restrict__ b,
                                             float* __restrict__ out,
                                             float* __restrict__ st, int M) {
  int row = blockIdx.x * 4 + (threadIdx.x >> 6);
  if (row >= M) return;
  int lane = threadIdx.x & 63;
  const float* rp = in + (size_t)row * CC;
  int c0 = lane * 4;
  f32x4 x[3];
#pragma unroll
  for (int s = 0; s < 3; ++s) x[s] = *(const f32x4*)(rp + s * 256 + c0);
  float sum = 0.f;
#pragma unroll
  for (int s = 0; s < 3; ++s)
#pragma unroll
    for (int j = 0; j < 4; ++j) sum += x[s][j];
  float mean = wave_sum(sum) * (1.0f / CC);
  float s2 = 0.f;
#pragma unroll
  for (int s = 0; s < 3; ++s)
#pragma unroll
    for (int j = 0; j < 4; ++j) { float d = x[s][j] - mean; s2 += d * d; }
  float rs = rsqrtf(wave_sum(s2) * (1.0f / CC) + EPSF);
  float* op = out + (size_t)row * CC;
  f32x4 o[3];
  float sum2 = 0.f;
#pragma unroll
  for (int s = 0; s < 3; ++s) {
    int cc = s * 256 + c0;
    f32x4 gg = *(const f32x4*)(g + cc);
    f32x4 bb = *(const f32x4*)(b + cc);
#pragma unroll
    for (int j = 0; j < 4; ++j) {
      o[s][j] = (x[s][j] - mean) * rs * gg[j] + bb[j];
      sum2 += o[s][j];
    }
    *(f32x4*)(op + cc) = o[s];
  }
  float mean2 = wave_sum(sum2) * (1.0f / CC);
  float q2 = 0.f;
#pragma unroll
  for (int s = 0; s < 3; ++s)
#pragma unroll
    for (int j = 0; j < 4; ++j) { float d = o[s][j] - mean2; q2 += d * d; }
  float rs2 = rsqrtf(wave_sum(q2) * (1.0f / CC) + EPSF);
  if (lane == 0) { st[2 * row] = mean2; st[2 * row + 1] = rs2; }
}

// ---------------- LN + q_shift + token-mix, bf16 outputs ----------------
// RAW: st holds (sum, sumsq) accumulated by the Wo-gemm epilogue (k_stats
// kernel eliminated); mean/rstd derived here. !RAW: st holds (mean, rstd).
template <int NOUT, bool RAW>
__global__ __launch_bounds__(256) void k_mix(const float* __restrict__ xb,
                                             const float* __restrict__ st,
                                             const float* __restrict__ g,
                                             const float* __restrict__ b,
                                             const float* __restrict__ mk,
                                             const float* __restrict__ mv,
                                             const float* __restrict__ mr,
                                             bf16_t* __restrict__ ok,
                                             bf16_t* __restrict__ ov,
                                             bf16_t* __restrict__ orr, int M) {
  int tok = blockIdx.x * 4 + (threadIdx.x >> 6);
  if (tok >= M) return;
  int lane = threadIdx.x & 63;
  int t = tok % TB;
  int h = t / HWD, w = t % HWD;
  int nbr[4];
  nbr[0] = (w > 0)       ? tok - 1   : -1;
  nbr[1] = (w < HWD - 1) ? tok + 1   : -1;
  nbr[2] = (h > 0)       ? tok - HWD : -1;
  nbr[3] = (h < HWD - 1) ? tok + HWD : -1;
  float ms, rss;
  {
    float a0 = st[2 * tok], a1 = st[2 * tok + 1];
    if (RAW) {
      ms = a0 * (1.0f / CC);
      float var = a1 * (1.0f / CC) - ms * ms;
      rss = rsqrtf(var + EPSF);
    } else { ms = a0; rss = a1; }
  }
  const float* rp = xb + (size_t)tok * CC;
#pragma unroll
  for (int s = 0; s < 3; ++s) {
    int cc = s * 256 + lane * 4;
    int grp = cc / 192;
    int nb = nbr[grp];
    f32x4 xs = *(const f32x4*)(rp + cc);
    f32x4 xn = {0.f, 0.f, 0.f, 0.f};
    float mn = 0.f, rsn = 0.f;
    if (nb >= 0) {
      xn = *(const f32x4*)(xb + (size_t)nb * CC + cc);
      float b0 = st[2 * nb], b1 = st[2 * nb + 1];
      if (RAW) {
        mn = b0 * (1.0f / CC);
        float var = b1 * (1.0f / CC) - mn * mn;
        rsn = rsqrtf(var + EPSF);
      } else { mn = b0; rsn = b1; }
    }
    f32x4 gg = *(const f32x4*)(g + cc);
    f32x4 bb = *(const f32x4*)(b + cc);
    f32x4 mk4 = *(const f32x4*)(mk + cc);
    f32x4 mr4 = *(const f32x4*)(mr + cc);
    f32x4 mv4 = {0.f, 0.f, 0.f, 0.f};
    if (NOUT == 3) mv4 = *(const f32x4*)(mv + cc);
    bf16x4 vk, vv, vr;
#pragma unroll
    for (int j = 0; j < 4; ++j) {
      float xi = (xs[j] - ms) * rss * gg[j] + bb[j];
      float xx = (nb >= 0) ? ((xn[j] - mn) * rsn * gg[j] + bb[j]) : 0.f;
      vk[j] = (bf16_t)(xi * mk4[j] + xx * (1.0f - mk4[j]));
      if (NOUT == 3) vv[j] = (bf16_t)(xi * mv4[j] + xx * (1.0f - mv4[j]));
      vr[j] = (bf16_t)(xi * mr4[j] + xx * (1.0f - mr4[j]));
    }
    *(bf16x4*)(ok + (size_t)tok * CC + cc) = vk;
    if (NOUT == 3) *(bf16x4*)(ov + (size_t)tok * CC + cc) = vv;
    *(bf16x4*)(orr + (size_t)tok * CC + cc) = vr;
  }
}

// ---------------- weight f32 (K,N) -> bf16 transposed (N,K) ----------------
__global__ __launch_bounds__(256) void k_tcvt(const float* __restrict__ src,
                                              bf16_t* __restrict__ dst, int K, int N) {
  __shared__ float tile[32][33];
  int tx = threadIdx.x & 31;
  int ty = threadIdx.x >> 5;
  int n0 = blockIdx.x * 32, k0 = blockIdx.y * 32;
#pragma unroll
  for (int i = 0; i < 4; ++i)
    tile[ty + 8 * i][tx] = src[(size_t)(k0 + ty + 8 * i) * N + n0 + tx];
  __syncthreads();
#pragma unroll
  for (int i = 0; i < 4; ++i)
    dst[(size_t)(n0 + ty + 8 * i) * K + k0 + tx] = (bf16_t)tile[tx][ty + 8 * i];
}

// z-batched 768x768 transposes (one launch for the 5 square weights)
struct TcvtPair { const float* src; bf16_t* dst; };
struct TcvtBatch { TcvtPair p[5]; };
__global__ __launch_bounds__(256) void k_tcvt5(TcvtBatch tb) {
  __shared__ float tile[32][33];
  TcvtPair pp = tb.p[blockIdx.z];
  int tx = threadIdx.x & 31;
  int ty = threadIdx.x >> 5;
  int n0 = blockIdx.x * 32, k0 = blockIdx.y * 32;
#pragma unroll
  for (int i = 0; i < 4; ++i)
    tile[ty + 8 * i][tx] = pp.src[(size_t)(k0 + ty + 8 * i) * 768 + n0 + tx];
  __syncthreads();
#pragma unroll
  for (int i = 0; i < 4; ++i)
    pp.dst[(size_t)(n0 + ty + 8 * i) * 768 + k0 + tx] = (bf16_t)tile[tx][ty + 8 * i];
}

// ---------------- MFMA GEMM: 128x128, BK=64, A-dbuf + B-single, 48 KiB, 3 blocks/CU ----------------
// Round-7 structure (session best). FROZEN except the EPI_ADD_STATS epilogue,
// which additionally accumulates per-row (sum, sumsq) of the post-add value
// into st2 via shuffle-reduce + atomics (replaces the k_stats kernel).
enum { EPI_F32 = 0, EPI_SIG_BF16 = 1, EPI_RELU2_BF16 = 2, EPI_ADD_STATS = 3, EPI_GATE = 4, EPI_BF16 = 5 };

struct GemmArgs {
  const bf16_t* A;
  const bf16_t* B;
  void* C;
  const bf16_t* gate;   // EPI_GATE
  const float* resid;   // EPI_GATE
  float* st2;           // EPI_ADD_STATS
  int epi;
  int NT;               // N = NT*128; per-arg so independent gemms fuse in one launch
};
struct GemmBatch { GemmArgs a[3]; };

__global__ __launch_bounds__(256, 3) void k_gemm(GemmBatch batch, int M, int K, int Mt) {
  __shared__ __align__(16) ushort_t sA[2][128 * 64];
  __shared__ __align__(16) ushort_t sB[128 * 64];
  int p = blockIdx.x, zi = 0;
  int nbk = Mt * batch.a[0].NT;
  while (p >= nbk && zi < 2) { p -= nbk; ++zi; nbk = Mt * batch.a[zi].NT; }
  GemmArgs ga = batch.a[zi];
  int NT = ga.NT;
  int N = NT << 7;
  int G = NT * 8, Mt8 = Mt & ~7;
  int m, n;
  if (p < Mt8 * NT) {
    int g = p / G;
    int r = p - g * G;
    m = g * 8 + (r & 7);
    n = r >> 3;
  } else {
    int r2 = p - Mt8 * NT;
    int rem = Mt - Mt8;
    m = Mt8 + r2 % rem;
    n = r2 / rem;
  }
  int bm = m << 7, bn = n << 7;
  int tid = threadIdx.x;
  int wave = tid >> 6, lane = tid & 63;
  int fr = lane & 15, fq = lane >> 4, fr7 = fr & 7;
  int wm = (wave >> 1) * 64, wn = (wave & 1) * 64;
  int r0 = tid >> 3;          // 0..31: base row for staging
  int pos = tid & 7;          // 16B chunk slot within the 128B LDS row
  int cs = pos ^ (r0 & 7);    // pre-swizzled source chunk ((r0+32j)&7 == r0&7)
  const bf16_t* Ab = ga.A + (size_t)bm * K;
  const bf16_t* Bb = ga.B + (size_t)bn * K;

  auto stageA = [&](int s, int kt) {
    int koff = kt * 64 + cs * 8;
#pragma unroll
    for (int j = 0; j < 4; ++j) {
      int row = j * 32 + r0;
      async_copy16(Ab + (size_t)row * K + koff, &sA[s][row * 64 + pos * 8]);
    }
  };
  auto stageB = [&](int kt) {
    int koff = kt * 64 + cs * 8;
#pragma unroll
    for (int j = 0; j < 4; ++j) {
      int row = j * 32 + r0;
      async_copy16(Bb + (size_t)row * K + koff, &sB[row * 64 + pos * 8]);
    }
  };

  f32x4 acc[4][4] = {};
  int niter = K >> 6;
  stageA(0, 0);
  stageB(0);
  SCHED_FENCE();
  asm volatile("s_waitcnt vmcnt(0)" ::: "memory");
  BAR();
  int buf = 0;
  for (int t = 0; t < niter; ++t) {
    // A(t) in sA[buf], B(t) in sB, both landed (tail vmcnt+BAR of prev iter).
    if (t + 1 < niter) stageA(buf ^ 1, t + 1);   // double-buffered: race-free early issue
    SCHED_FENCE();
    bf16x8 bfv[4][2];
#pragma unroll
    for (int i = 0; i < 4; ++i) {
      int rb = wn + i * 16 + fr;
#pragma unroll
      for (int ks = 0; ks < 2; ++ks)
        bfv[i][ks] = *(const bf16x8*)&sB[rb * 64 + (((ks * 4 + fq) ^ fr7) << 3)];
    }
    LGKM0();            // own B reads done
    BAR();              // ALL waves' B reads done -> sB safe to overwrite
    if (t + 1 < niter) stageB(t + 1);
    SCHED_FENCE();
    bf16x8 af[4][2];
#pragma unroll
    for (int i = 0; i < 4; ++i) {
      int ra = wm + i * 16 + fr;
#pragma unroll
      for (int ks = 0; ks < 2; ++ks)
        af[i][ks] = *(const bf16x8*)&sA[buf][ra * 64 + (((ks * 4 + fq) ^ fr7) << 3)];
    }
    LGKM0();
#pragma unroll
    for (int ks = 0; ks < 2; ++ks)
#pragma unroll
      for (int mi = 0; mi < 4; ++mi)
#pragma unroll
        for (int ni = 0; ni < 4; ++ni)
          acc[mi][ni] = __builtin_amdgcn_mfma_f32_16x16x32_bf16(af[mi][ks], bfv[ni][ks], acc[mi][ni], 0, 0, 0);
    asm volatile("s_waitcnt vmcnt(0)" ::: "memory");  // A(t+1), B(t+1) landed
    BAR();
    buf ^= 1;
  }
  int epi = ga.epi;
  if (epi == EPI_ADD_STATS) {
    // Wo residual-add + fused row stats: per (mi,r) row, sum this wave's
    // 64-col slice over ni, shuffle-reduce across the 16 fr-lanes (stays in
    // fq group), then one atomicAdd pair per (row, fq-group).
    float* C = (float*)ga.C;
#pragma unroll
    for (int mi = 0; mi < 4; ++mi) {
#pragma unroll
      for (int r = 0; r < 4; ++r) {
        int grow = bm + wm + mi * 16 + fq * 4 + r;
        float s1 = 0.f, s2 = 0.f;
#pragma unroll
        for (int ni = 0; ni < 4; ++ni) {
          int gcol = bn + wn + ni * 16 + fr;
          size_t idx = (size_t)grow * N + gcol;
          float fin = C[idx] + acc[mi][ni][r];
          C[idx] = fin;
          s1 += fin;
          s2 += fin * fin;
        }
#pragma unroll
        for (int off = 1; off < 16; off <<= 1) {
          s1 += __shfl_xor(s1, off, 64);
          s2 += __shfl_xor(s2, off, 64);
        }
        if (fr == 0) {
          atomicAdd(&ga.st2[2 * grow], s1);
          atomicAdd(&ga.st2[2 * grow + 1], s2);
        }
      }
    }
  } else {
#pragma unroll
    for (int mi = 0; mi < 4; ++mi) {
#pragma unroll
      for (int ni = 0; ni < 4; ++ni) {
#pragma unroll
        for (int r = 0; r < 4; ++r) {
          int grow = bm + wm + mi * 16 + fq * 4 + r;
          int gcol = bn + wn + ni * 16 + fr;
          size_t idx = (size_t)grow * N + gcol;
          float v = acc[mi][ni][r];
          if (epi == EPI_F32) {
            ((float*)ga.C)[idx] = v;
          } else if (epi == EPI_BF16) {
            ((bf16_t*)ga.C)[idx] = (bf16_t)v;
          } else if (epi == EPI_SIG_BF16) {
            ((bf16_t*)ga.C)[idx] = (bf16_t)(1.0f / (1.0f + __expf(-v)));
          } else if (epi == EPI_RELU2_BF16) {
            float tv = v > 0.f ? v : 0.f;
            ((bf16_t*)ga.C)[idx] = (bf16_t)(tv * tv);
          } else {  // EPI_GATE: out = resid + sigmoid-gate * v
            ((float*)ga.C)[idx] = ga.resid[idx] + (float)ga.gate[idx] * v;
          }
        }
      }
    }
  }
}

// ---------------- fused bidirectional WKV (bwd scan then fwd scan, same thread) ----------------
// 14-wide load batching (TB = 14x14) + distance-1 group prefetch; V type is
// templated so the CB=128 layout can store V as bf16 (K stays f32: it feeds exp).
#define WG 14

template <typename VT>
__global__ __launch_bounds__(64) void k_wkv(const float* __restrict__ k,
                                            const VT* __restrict__ v,
                                            const float* __restrict__ decay,
                                            const float* __restrict__ first,
                                            bf16_t* __restrict__ ba,
                                            bf16_t* __restrict__ bb,
                                            bf16_t* __restrict__ r, int CB) {
  int idx = blockIdx.x * 64 + threadIdx.x;
  if (idx >= CB * CC) return;
  int c = idx % CC;
  size_t base = (size_t)(idx / CC) * TB * CC + c;
  float w = decay[c] * INV_T;
  float d = __expf(-w);
  float a = 0.f, bs = 0.f;
  {
    float ck[WG], cv[WG], nk[WG], nv[WG];
    int tg = TB - WG;
#pragma unroll
    for (int j = 0; j < WG; ++j) {
      size_t p = base + (size_t)(tg + j) * CC;
      ck[j] = k[p]; cv[j] = (float)v[p];
    }
    for (; tg >= 0; tg -= WG) {
      int tn = tg - WG;
      if (tn >= 0) {
#pragma unroll
        for (int j = 0; j < WG; ++j) {
          size_t p = base + (size_t)(tn + j) * CC;
          nk[j] = k[p]; nv[j] = (float)v[p];
        }
      }
#pragma unroll
      for (int j = WG - 1; j >= 0; --j) {
        size_t p = base + (size_t)(tg + j) * CC;
        ba[p] = (bf16_t)a;
        bb[p] = (bf16_t)bs;
        float ek = __expf(ck[j]);
        a = d * (a + ek * cv[j]);
        bs = d * (bs + ek);
      }
#pragma unroll
      for (int j = 0; j < WG; ++j) { ck[j] = nk[j]; cv[j] = nv[j]; }
    }
  }
  float ew = __expf(w);
  float euc = __expf(first[c] * INV_T);   // exp(u); eu = euc * exp(k) (1 exp/step)
  a = 0.f; bs = 0.f;
  {
    float ck[WG], cv[WG], pa[WG], pb[WG];
    float nk[WG], nv[WG], na[WG], nb[WG];
#pragma unroll
    for (int j = 0; j < WG; ++j) {
      size_t p = base + (size_t)j * CC;
      ck[j] = k[p]; cv[j] = (float)v[p];
      pa[j] = (float)ba[p]; pb[j] = (float)bb[p];
    }
    for (int tg = 0; tg < TB; tg += WG) {
      int tn = tg + WG;
      if (tn < TB) {
#pragma unroll
        for (int j = 0; j < WG; ++j) {
          size_t p = base + (size_t)(tn + j) * CC;
          nk[j] = k[p]; nv[j] = (float)v[p];
          na[j] = (float)ba[p]; nb[j] = (float)bb[p];
        }
      }
#pragma unroll
      for (int j = 0; j < WG; ++j) {
        size_t p = base + (size_t)(tg + j) * CC;
        float ek = __expf(ck[j]);
        float eu = euc * ek;
        float num = ew * (a + pa[j]) + eu * cv[j];
        float den = ew * (bs + pb[j]) + eu;
        r[p] = (bf16_t)(num / den);
        a = d * (a + ek * cv[j]);
        bs = d * (bs + ek);
      }
#pragma unroll
      for (int j = 0; j < WG; ++j) { ck[j] = nk[j]; cv[j] = nv[j]; pa[j] = na[j]; pb[j] = nb[j]; }
    }
  }
}

// ---------------- LN(rwkv bf16) * sr -> bf16; also zeroes st2 for the Wo-epilogue stats ----------------
__global__ __launch_bounds__(256) void k_ln_mul(const bf16_t* __restrict__ in,
                                                const bf16_t* __restrict__ sr,
                                                const float* __restrict__ g,
                                                const float* __restrict__ b,
                                                bf16_t* __restrict__ out,
                                                float* __restrict__ stz, int M) {
  int row = blockIdx.x * 4 + (threadIdx.x >> 6);
  if (row >= M) return;
  int lane = threadIdx.x & 63;
  if (lane == 0) { stz[2 * row] = 0.f; stz[2 * row + 1] = 0.f; }
  const bf16_t* rp = in + (size_t)row * CC;
  int c0 = lane * 4;
  float x[12];
#pragma unroll
  for (int s = 0; s < 3; ++s) {
    bf16x4 t = *(const bf16x4*)(rp + s * 256 + c0);
#pragma unroll
    for (int j = 0; j < 4; ++j) x[s * 4 + j] = (float)t[j];
  }
  float sum = 0.f;
#pragma unroll
  for (int i = 0; i < 12; ++i) sum += x[i];
  float mean = wave_sum(sum) * (1.0f / CC);
  float s2 = 0.f;
#pragma unroll
  for (int i = 0; i < 12; ++i) { float d = x[i] - mean; s2 += d * d; }
  float rs = rsqrtf(wave_sum(s2) * (1.0f / CC) + EPSF);
#pragma unroll
  for (int s = 0; s < 3; ++s) {
    int cc = s * 256 + c0;
    f32x4 gg = *(const f32x4*)(g + cc);
    f32x4 bb = *(const f32x4*)(b + cc);
    bf16x4 s4 = *(const bf16x4*)(sr + (size_t)row * CC + cc);
    bf16x4 o;
#pragma unroll
    for (int j = 0; j < 4; ++j)
      o[j] = (bf16_t)(((x[s * 4 + j] - mean) * rs * gg[j] + bb[j]) * (float)s4[j]);
    *(bf16x4*)(out + (size_t)row * CC + cc) = o;
  }
}

// ---------------- LN over HID=3072 bf16 rows, IN-PLACE ----------------
__global__ __launch_bounds__(256) void k_ln_hid(bf16_t* __restrict__ io,
                                                const float* __restrict__ g,
                                                const float* __restrict__ b, int M) {
  int row = blockIdx.x * 4 + (threadIdx.x >> 6);
  if (row >= M) return;
  int lane = threadIdx.x & 63;
  bf16_t* rp = io + (size_t)row * HD;
  int c0 = lane * 8;
  bf16x8 x[6];
#pragma unroll
  for (int s = 0; s < 6; ++s) x[s] = *(const bf16x8*)(rp + s * 512 + c0);
  float sum = 0.f;
#pragma unroll
  for (int s = 0; s < 6; ++s)
#pragma unroll
    for (int j = 0; j < 8; ++j) sum += (float)x[s][j];
  float mean = wave_sum(sum) * (1.0f / HD);
  float s2 = 0.f;
#pragma unroll
  for (int s = 0; s < 6; ++s)
#pragma unroll
    for (int j = 0; j < 8; ++j) { float d = (float)x[s][j] - mean; s2 += d * d; }
  float rs = rsqrtf(wave_sum(s2) * (1.0f / HD) + EPSF);
#pragma unroll
  for (int s = 0; s < 6; ++s) {
    int cc = s * 512 + c0;
    f32x4 g0 = *(const f32x4*)(g + cc);
    f32x4 g1 = *(const f32x4*)(g + cc + 4);
    f32x4 b0 = *(const f32x4*)(b + cc);
    f32x4 b1 = *(const f32x4*)(b + cc + 4);
    bf16x8 o;
#pragma unroll
    for (int j = 0; j < 4; ++j) {
      o[j]     = (bf16_t)(((float)x[s][j]     - mean) * rs * g0[j] + b0[j]);
      o[j + 4] = (bf16_t)(((float)x[s][j + 4] - mean) * rs * g1[j] + b1[j]);
    }
    *(bf16x8*)(rp + cc) = o;
  }
}

// ---------------- host orchestration ----------------
// Layout B/elem of MC: big = [K32(4)|V(4 or 2)|SR16(2)] union [KFa(8)];
// a16/b16/c16 = 2 each. v16 variant: 14 B/elem total -> CB=128 fits at
// ws >= ~288 MB (V bf16 only on that path; K stays f32 for exp precision).
struct Layout {
  size_t wk, wv, wr, wo, fk, fv, fr;
  size_t st, big, a16, b16, c16;
  size_t end;
};

static Layout make_layout(int CB, int v16) {
  Layout L;
  size_t off = 0;
  auto al = [&](size_t bytes) { size_t o = (off + 255) & ~(size_t)255; off = o + bytes; return o; };
  L.wk = al(589824ull * 2);
  L.wv = al(589824ull * 2);
  L.wr = al(589824ull * 2);
  L.wo = al(589824ull * 2);
  L.fk = al(2359296ull * 2);
  L.fv = al(2359296ull * 2);
  L.fr = al(589824ull * 2);
  size_t M = (size_t)CB * 196;
  size_t MC = M * 768;
  L.st  = al(M * 8);
  L.big = al(MC * (v16 ? 8 : 10));
  L.a16 = al(MC * 2);
  L.b16 = al(MC * 2);
  L.c16 = al(MC * 2);
  L.end = off;
  return L;
}

extern "C" void kernel_launch(void* const* d_in, const int* in_sizes, int n_in,
                              void* d_out, int out_size, void* d_ws, size_t ws_size,
                              hipStream_t stream) {
  const float* x      = (const float*)d_in[0];
  const float* ln0_g  = (const float*)d_in[1];
  const float* ln0_b  = (const float*)d_in[2];
  const float* ln1_g  = (const float*)d_in[3];
  const float* ln1_b  = (const float*)d_in[4];
  const float* ln2_g  = (const float*)d_in[5];
  const float* ln2_b  = (const float*)d_in[6];
  const float* amk    = (const float*)d_in[7];
  const float* amv    = (const float*)d_in[8];
  const float* amr    = (const float*)d_in[9];
  const float* adec   = (const float*)d_in[10];
  const float* afirst = (const float*)d_in[11];
  const float* aWk    = (const float*)d_in[12];
  const float* aWv    = (const float*)d_in[13];
  const float* aWr    = (const float*)d_in[14];
  const float* aWo    = (const float*)d_in[15];
  const float* akn_g  = (const float*)d_in[16];
  const float* akn_b  = (const float*)d_in[17];
  const float* fmk    = (const float*)d_in[18];
  const float* fmr    = (const float*)d_in[19];
  const float* fWk    = (const float*)d_in[20];
  const float* fWv    = (const float*)d_in[21];
  const float* fWr    = (const float*)d_in[22];
  const float* fkn_g  = (const float*)d_in[23];
  const float* fkn_b  = (const float*)d_in[24];

  int CB = 32, V16 = 0;
  if (make_layout(128, 0).end <= ws_size)      { CB = 128; V16 = 0; }
  else if (make_layout(128, 1).end <= ws_size) { CB = 128; V16 = 1; }
  else if (make_layout(64, 0).end <= ws_size)  { CB = 64;  V16 = 0; }
  Layout L = make_layout(CB, V16);
  int nchunk = 128 / CB;
  int M = CB * 196;
  size_t MC = (size_t)M * 768;

  uint8_t* ws = (uint8_t*)d_ws;
  bf16_t* WkT = (bf16_t*)(ws + L.wk);
  bf16_t* WvT = (bf16_t*)(ws + L.wv);
  bf16_t* WrT = (bf16_t*)(ws + L.wr);
  bf16_t* WoT = (bf16_t*)(ws + L.wo);
  bf16_t* FkT = (bf16_t*)(ws + L.fk);
  bf16_t* FvT = (bf16_t*)(ws + L.fv);
  bf16_t* FrT = (bf16_t*)(ws + L.fr);
  float*  ST  = (float*)(ws + L.st);
  uint8_t* big = ws + L.big;
  float*  K32 = (float*)(big);
  void*   Vbuf = (void*)(big + MC * 4);
  bf16_t* SR16 = (bf16_t*)(big + MC * (V16 ? 6 : 8));
  bf16_t* KFa = (bf16_t*)(big);            // M x 3072 bf16 (aliases K/V/SR, dead by then)
  bf16_t* A16 = (bf16_t*)(ws + L.a16);
  bf16_t* B16 = (bf16_t*)(ws + L.b16);
  bf16_t* C16 = (bf16_t*)(ws + L.c16);
  // dead-window aliases: P/Q/R live in the xk/xv/xr buffers (consumed by QKV gemm)
  bf16_t* P16 = A16;
  bf16_t* Q16 = B16;
  bf16_t* R16 = C16;

  {
    TcvtBatch tb;
    tb.p[0] = {aWk, WkT}; tb.p[1] = {aWv, WvT}; tb.p[2] = {aWr, WrT};
    tb.p[3] = {aWo, WoT}; tb.p[4] = {fWr, FrT};
    k_tcvt5<<<dim3(24, 24, 5), 256, 0, stream>>>(tb);
  }
  k_tcvt<<<dim3(96, 24), 256, 0, stream>>>(fWk, FkT, 768, 3072);
  k_tcvt<<<dim3(24, 96), 256, 0, stream>>>(fWv, FvT, 3072, 768);

  int rowb = M / 4;
  int Mt = M / 128;
  int wkvb = (CB * 768) / 64;   // 64-thread blocks

  for (int ch = 0; ch < nchunk; ++ch) {
    const float* xin = x + (size_t)ch * MC;
    float* XB = (float*)d_out + (size_t)ch * MC;   // residual stream lives in d_out

    // ---- attention half ----
    k_ln0<<<rowb, 256, 0, stream>>>(xin, ln0_g, ln0_b, XB, ST, M);
    k_mix<3, false><<<rowb, 256, 0, stream>>>(XB, ST, ln1_g, ln1_b, amk, amv, amr, A16, B16, C16, M);
    {
      GemmBatch gb{};
      gb.a[0] = {A16, WkT, K32, nullptr, nullptr, nullptr, EPI_F32, 6};
      gb.a[1] = {B16, WvT, Vbuf, nullptr, nullptr, nullptr, V16 ? EPI_BF16 : EPI_F32, 6};
      gb.a[2] = {C16, WrT, SR16, nullptr, nullptr, nullptr, EPI_SIG_BF16, 6};
      k_gemm<<<dim3(Mt * 18), 256, 0, stream>>>(gb, M, 768, Mt);
    }
    // A16/B16/C16 (xk/xv/xr) are dead now -> reuse as P16/Q16/R16
    if (V16)
      k_wkv<bf16_t><<<wkvb, 64, 0, stream>>>(K32, (const bf16_t*)Vbuf, adec, afirst, P16, Q16, R16, CB);
    else
      k_wkv<float><<<wkvb, 64, 0, stream>>>(K32, (const float*)Vbuf, adec, afirst, P16, Q16, R16, CB);
    // ln_mul reads R16(=C16) + SR16, writes A16; zeroes ST for Wo's fused stats
    k_ln_mul<<<rowb, 256, 0, stream>>>(R16, SR16, akn_g, akn_b, A16, ST, M);
    {
      GemmBatch gb{};
      gb.a[0] = {A16, WoT, XB, nullptr, nullptr, ST, EPI_ADD_STATS, 6};
      k_gemm<<<dim3(Mt * 6), 256, 0, stream>>>(gb, M, 768, Mt);
    }

    // ---- ffn half (row stats arrive pre-accumulated in ST as sum/sumsq) ----
    k_mix<2, true><<<rowb, 256, 0, stream>>>(XB, ST, ln2_g, ln2_b, fmk, nullptr, fmr, A16, nullptr, C16, M);
    {
      // FFN-K (NT=24) and Wr (NT=6) are independent: fuse into one launch
      GemmBatch gb{};
      gb.a[0] = {A16, FkT, KFa, nullptr, nullptr, nullptr, EPI_RELU2_BF16, 24};
      gb.a[1] = {C16, FrT, B16, nullptr, nullptr, nullptr, EPI_SIG_BF16, 6};
      k_gemm<<<dim3(Mt * 30), 256, 0, stream>>>(gb, M, 768, Mt);
    }
    k_ln_hid<<<rowb, 256, 0, stream>>>(KFa, fkn_g, fkn_b, M);   // in-place
    {
      GemmBatch gb{};
      gb.a[0] = {KFa, FvT, XB, B16, XB, nullptr, EPI_GATE, 6};
      k_gemm<<<dim3(Mt * 6), 256, 0, stream>>>(gb, M, 3072, Mt);
    }
  }
}